// Round 2
// baseline (3134.272 us; speedup 1.0000x reference)
//
#include <hip/hip_runtime.h>

typedef __attribute__((ext_vector_type(8)))  short          bf16x8;
typedef __attribute__((ext_vector_type(16))) float          f32x16;
typedef __attribute__((ext_vector_type(8)))  unsigned int   u32x8;
typedef __attribute__((ext_vector_type(4)))  unsigned short ushort4v;
typedef __attribute__((ext_vector_type(4)))  float          float4v;

#define DEV static __device__ __forceinline__
#define MFMA32(A,B,C) __builtin_amdgcn_mfma_f32_32x32x16_bf16(A,B,C,0,0,0)

// ---- workspace element offsets (unsigned short elements) ----
#define WRES_OFF 0u           // 49 layers * 49 taps * 64*64        = 9,834,496
#define FW_OFF   9834496u     // 49 taps * 64 o * 16 c              =    50,176
#define LW_OFF   9884672u     // 7 * 64 * 64                        =    28,672
#define P1_OFF   9913344u     // 256 * 2048                         =   524,288
#define P2_OFF   10437632u    // 1792 * 256 (padded rows)           =   458,752
#define ACT0_OFF 10896384u    // 1024 * 64p * 64c                   = 4,194,304
#define PV_OFF   15090688u    // 1024 * 32 * 64                     = 2,097,152
#define HID_OFF  17187840u    // 1024 * 256                         =   262,144
// total 17,449,984 ushorts = 34.9 MB

// ---- d_out offsets (floats) ----
#define VAL_OFF 1740800
#define PID_OFF 1741824

// ---- tower LDS map ----
#define SM_Z     57344      // 128B zero row (after 4 * 14336 act buffers)
#define SM_XIN   57472      // 4 * 3584 first-conv input staging
#define SM_BYTES 71808

DEV float bf2f(unsigned short u){ union { unsigned int i; float f; } v; v.i = ((unsigned int)u) << 16; return v.f; }
DEV unsigned short f2bf(float f){
  union { float f; unsigned int i; } v; v.f = f;
  unsigned int x = v.i;
  return (unsigned short)((x + 0x7fffu + ((x >> 16) & 1u)) >> 16);  // RNE
}

// ======================= weight prep =======================
// res_w (7,7,64,64,7,7) f32 -> fragment-major wres[L][t][ks*2+mt][lane(64)][8] bf16
// element (lane,j) of frag (ks,mt) = W[o = mt*32 + (lane&31)][c = ks*16 + (lane>>5)*8 + j]
__global__ void prep_res_k(const float* __restrict__ res_w, unsigned short* __restrict__ ws){
  __shared__ float buf[3136];
  int bx = blockIdx.x;             // L*64 + o
  int L = bx >> 6, o = bx & 63;
  const float* src = res_w + (size_t)bx * 3136;   // (o fixed): [c][dy][dx] contiguous
  for (int e = threadIdx.x; e < 3136; e += 256) buf[e] = src[e];
  __syncthreads();
  unsigned short* dst = ws + WRES_OFF;
  int mt = o >> 5, lrow = o & 31;
  for (int e = threadIdx.x; e < 3136; e += 256){
    int t = e >> 6, c = e & 63;
    int ks = c >> 4, hi = (c >> 3) & 1, j = c & 7;
    int lane = hi*32 + lrow;
    dst[(size_t)(L*49 + t)*4096 + ((ks*2 + mt)*64 + lane)*8 + j] = f2bf(buf[c*49 + t]);
  }
}

// first_w -> fw[t][mt][lane][8] (K=16: c = (lane>>5)*8+j, 12 real + 4 zero)
// last_w  -> lw[st][ks*2+mt][lane][8]
// pfc1/pfc2 cast (+pad)
__global__ void prep_misc_k(const float* __restrict__ first_w, const float* __restrict__ last_w,
                            const float* __restrict__ pfc1_w, const float* __restrict__ pfc2_w,
                            unsigned short* __restrict__ ws){
  const int n_fw = 49*1024, n_lw = 28672, n_p1 = 524288, n_p2 = 458752;
  const int total = n_fw + n_lw + n_p1 + n_p2;
  for (int d = blockIdx.x*256 + threadIdx.x; d < total; d += gridDim.x*256){
    if (d < n_fw){
      int t = d >> 10, r = d & 1023;
      int mt = r >> 9, lane = (r >> 3) & 63, j = r & 7;
      int o = mt*32 + (lane & 31);
      int c = ((lane >> 5) << 3) + j;
      float v = (o < 63 && c < 12) ? first_w[(o*12 + c)*49 + t] : 0.f;
      ws[FW_OFF + d] = f2bf(v);
    } else if (d < n_fw + n_lw){
      int e = d - n_fw;
      int st = e >> 12, r = e & 4095;
      int f = r >> 9, lane = (r >> 3) & 63, j = r & 7;
      int ks = f >> 1, mt = f & 1;
      int o = mt*32 + (lane & 31);
      int c = ks*16 + ((lane >> 5) << 3) + j;
      ws[LW_OFF + e] = f2bf(last_w[st*4096 + o*64 + c]);
    } else if (d < n_fw + n_lw + n_p1){
      int e = d - n_fw - n_lw; ws[P1_OFF + e] = f2bf(pfc1_w[e]);
    } else {
      int e = d - n_fw - n_lw - n_p1;
      int row = e >> 8, k = e & 255;
      ws[P2_OFF + e] = f2bf(row < 1700 ? pfc2_w[row*256 + k] : 0.f);
    }
  }
}

// ======================= tower =======================
DEV int baddr(int q, bool valid, int imgbase, int hi){
  int sz = (q & 7) << 4;
  int a = (q << 7) + ((imgbase + hi*16) ^ sz);
  return valid ? a : (SM_Z + hi*16);
}

DEV void conv64(unsigned char* smp, const unsigned short* wt,
                f32x16& A00, f32x16& A01, f32x16& A10, f32x16& A11,
                int qb0, int qb1, int y0, int y1, int imgbase, int hi, int lane){
  #pragma unroll
  for (int dy = 0; dy < 7; ++dy){
    bool v0 = (unsigned)(y0 + dy - 3) < 8u;
    bool v1 = (unsigned)(y1 + dy - 3) < 8u;
    int tq = (dy-3)*14;
    #pragma unroll
    for (int dx = 0; dx < 7; ++dx){
      const unsigned short* wtt = wt + (dy*7 + dx)*4096;
      bf16x8 a0k[4], a1k[4];
      #pragma unroll
      for (int ks = 0; ks < 4; ++ks){
        a0k[ks] = *(const bf16x8*)(wtt + (ks*2    )*512 + lane*8);
        a1k[ks] = *(const bf16x8*)(wtt + (ks*2 + 1)*512 + lane*8);
      }
      int b0 = baddr(qb0 + tq + dx, v0, imgbase, hi);
      int b1 = baddr(qb1 + tq + dx, v1, imgbase, hi);
      #pragma unroll
      for (int ks = 0; ks < 4; ++ks){
        bf16x8 bf0 = *(const bf16x8*)(smp + (b0 ^ (ks << 5)));
        bf16x8 bf1 = *(const bf16x8*)(smp + (b1 ^ (ks << 5)));
        A00 = MFMA32(a0k[ks], bf0, A00);
        A01 = MFMA32(a0k[ks], bf1, A01);
        A10 = MFMA32(a1k[ks], bf0, A10);
        A11 = MFMA32(a1k[ks], bf1, A11);
      }
    }
  }
}

DEV void conv_epi(const f32x16& acc, int mt, int qb, int imgbase, int hi,
                  unsigned char* smp, const float* sp, const float* bp){
  int qw = qb + 3; int swzw = (qw & 7) << 4; int rowb = imgbase + (qw << 7);
  #pragma unroll
  for (int rg = 0; rg < 4; ++rg){
    int o0 = mt*32 + rg*8 + hi*4;
    unsigned short bb[4];
    #pragma unroll
    for (int e = 0; e < 4; ++e){
      float v = sp[o0+e]*acc[rg*4+e] + bp[o0+e];
      v = v > 0.f ? v : 0.f;
      bb[e] = f2bf(v);
    }
    int ob = mt*64 + rg*16 + hi*8;
    *(ushort4v*)(smp + rowb + (ob ^ swzw)) = ushort4v{bb[0],bb[1],bb[2],bb[3]};
  }
}

DEV void res_epi(const f32x16& acc, u32x8& res, int mt, int qb, int imgbase, int hi,
                 unsigned char* smp, const float* lsp, const float* lbp){
  int qw = qb + 3; int swzw = (qw & 7) << 4; int rowb = imgbase + (qw << 7);
  #pragma unroll
  for (int rg = 0; rg < 4; ++rg){
    int o0 = mt*32 + rg*8 + hi*4;
    unsigned short bb[4];
    #pragma unroll
    for (int e = 0; e < 4; ++e){
      unsigned pr = res[rg*2 + (e>>1)];
      float rv = bf2f((unsigned short)((e & 1) ? (pr >> 16) : (pr & 0xffffu)));
      float v = lsp[o0+e]*acc[rg*4+e] + lbp[o0+e] + rv;
      v = v > 0.f ? v : 0.f;
      bb[e] = f2bf(v);
    }
    res[rg*2]   = (unsigned)bb[0] | ((unsigned)bb[1] << 16);
    res[rg*2+1] = (unsigned)bb[2] | ((unsigned)bb[3] << 16);
    int ob = mt*64 + rg*16 + hi*8;
    *(ushort4v*)(smp + rowb + (ob ^ swzw)) = ushort4v{bb[0],bb[1],bb[2],bb[3]};
  }
}

DEV void first_epi(const f32x16& acc, u32x8& res, int mt, int qb, int p, float idsv,
                   int img, int imgbase, int hi, unsigned char* smp,
                   const float* fsp, const float* fbp, unsigned short* act0){
  int qw = qb + 3; int swzw = (qw & 7) << 4; int rowb = imgbase + (qw << 7);
  #pragma unroll
  for (int rg = 0; rg < 4; ++rg){
    int o0 = mt*32 + rg*8 + hi*4;
    unsigned short bb[4];
    #pragma unroll
    for (int e = 0; e < 4; ++e){
      int o = o0 + e;
      int oc = o < 63 ? o : 62;          // avoid OOB load of 63-entry arrays
      float v = fsp[oc]*acc[rg*4+e] + fbp[oc];
      v = v > 0.f ? v : 0.f;
      if (o == 63) v = idsv;             // ids channel, no bn/relu
      bb[e] = f2bf(v);
    }
    res[rg*2]   = (unsigned)bb[0] | ((unsigned)bb[1] << 16);
    res[rg*2+1] = (unsigned)bb[2] | ((unsigned)bb[3] << 16);
    int ob = mt*64 + rg*16 + hi*8;
    *(ushort4v*)(smp + rowb + (ob ^ swzw)) = ushort4v{bb[0],bb[1],bb[2],bb[3]};
    *(ushort4v*)(act0 + (size_t)img*4096 + p*64 + o0) = ushort4v{bb[0],bb[1],bb[2],bb[3]};
  }
}

__global__ __launch_bounds__(256, 1) void tower_k(
    const float* __restrict__ x,
    const float* __restrict__ first_s, const float* __restrict__ first_b,
    const float* __restrict__ res_s,   const float* __restrict__ res_b,
    const float* __restrict__ last_s,  const float* __restrict__ last_b,
    const float* __restrict__ vconv_w, const float* __restrict__ v_s, const float* __restrict__ v_b,
    const float* __restrict__ vfc1_w,  const float* __restrict__ vfc1_b,
    const float* __restrict__ vfc2_w,  const float* __restrict__ vfc2_b,
    const unsigned short* ws_r, unsigned short* act0, float* value_out)
{
  __shared__ unsigned char sm[SM_BYTES];
  int tid = threadIdx.x, lane = tid & 63, wave = tid >> 6;
  int img = blockIdx.x * 4 + wave;

  for (int i = tid*16; i < SM_BYTES; i += 256*16) *(float4v*)(sm + i) = float4v{0,0,0,0};
  __syncthreads();

  int col = lane & 31, hi = lane >> 5;
  int imgbase = wave * 14336;
  int xinbase = SM_XIN + wave * 3584;

  int p0 = col, p1c = 32 + col;
  int y0 = p0 >> 3, y1 = p1c >> 3;
  int qb0 = y0*14 + (p0 & 7), qb1 = y1*14 + (p1c & 7);

  // ---- stage x into padded xin (bf16), channels 0..11 ----
  const float* xim = x + (size_t)img * 832;
  {
    int q = (lane >> 3)*14 + (lane & 7) + 3;
    for (int c = 0; c < 12; ++c){
      *(unsigned short*)(sm + xinbase + q*32 + c*2) = f2bf(xim[c*64 + lane]);
    }
  }
  float ids0 = xim[768 + p0];
  float ids1 = xim[768 + p1c];

  // ---- first conv (K=16: 12 real + 4 zero channels) ----
  f32x16 f00 = {}, f01 = {}, f10 = {}, f11 = {};
  const unsigned short* fw = ws_r + FW_OFF;
  #pragma unroll
  for (int dy = 0; dy < 7; ++dy){
    bool v0 = (unsigned)(y0 + dy - 3) < 8u;
    bool v1 = (unsigned)(y1 + dy - 3) < 8u;
    int tq = (dy-3)*14;
    #pragma unroll
    for (int dx = 0; dx < 7; ++dx){
      int t = dy*7 + dx;
      bf16x8 a0 = *(const bf16x8*)(fw + t*1024 +       lane*8);
      bf16x8 a1 = *(const bf16x8*)(fw + t*1024 + 512 + lane*8);
      int q0 = qb0 + tq + dx, q1 = qb1 + tq + dx;
      int b0a = v0 ? (xinbase + (q0 << 5) + hi*16) : (SM_Z + hi*16);
      int b1a = v1 ? (xinbase + (q1 << 5) + hi*16) : (SM_Z + hi*16);
      bf16x8 bb0 = *(const bf16x8*)(sm + b0a);
      bf16x8 bb1 = *(const bf16x8*)(sm + b1a);
      f00 = MFMA32(a0, bb0, f00);
      f01 = MFMA32(a0, bb1, f01);
      f10 = MFMA32(a1, bb0, f10);
      f11 = MFMA32(a1, bb1, f11);
    }
  }
  u32x8 res00, res01, res10, res11;
  first_epi(f00, res00, 0, qb0, p0,  ids0, img, imgbase, hi, sm, first_s, first_b, act0);
  first_epi(f01, res01, 0, qb1, p1c, ids1, img, imgbase, hi, sm, first_s, first_b, act0);
  first_epi(f10, res10, 1, qb0, p0,  ids0, img, imgbase, hi, sm, first_s, first_b, act0);
  first_epi(f11, res11, 1, qb1, p1c, ids1, img, imgbase, hi, sm, first_s, first_b, act0);

  // ---- residual tower ----
  for (int st = 0; st < 7; ++st){
    for (int j = 0; j < 7; ++j){
      int L = st*7 + j;
      // keep the block's 4 waves loosely in lockstep so they share the
      // current tap's 8KB weight tile in L1 (no data exchange).
      __builtin_amdgcn_s_barrier();
      const unsigned short* wt = ws_r + WRES_OFF + (size_t)L*200704u;
      f32x16 c00 = {}, c01 = {}, c10 = {}, c11 = {};
      conv64(sm, wt, c00, c01, c10, c11, qb0, qb1, y0, y1, imgbase, hi, lane);
      const float* sp = res_s + L*64;
      const float* bp = res_b + L*64;
      conv_epi(c00, 0, qb0, imgbase, hi, sm, sp, bp);
      conv_epi(c01, 0, qb1, imgbase, hi, sm, sp, bp);
      conv_epi(c10, 1, qb0, imgbase, hi, sm, sp, bp);
      conv_epi(c11, 1, qb1, imgbase, hi, sm, sp, bp);
    }
    // 1x1 (last_w) + bn + residual + relu
    const unsigned short* lw = ws_r + LW_OFF + st*4096;
    const float* lsp = last_s + st*64;
    const float* lbp = last_b + st*64;
    f32x16 c00 = {}, c01 = {}, c10 = {}, c11 = {};
    int bA = baddr(qb0 + 3, true, imgbase, hi);
    int bB = baddr(qb1 + 3, true, imgbase, hi);
    #pragma unroll
    for (int ks = 0; ks < 4; ++ks){
      bf16x8 a0 = *(const bf16x8*)(lw + (ks*2    )*512 + lane*8);
      bf16x8 a1 = *(const bf16x8*)(lw + (ks*2 + 1)*512 + lane*8);
      bf16x8 b0 = *(const bf16x8*)(sm + (bA ^ (ks << 5)));
      bf16x8 b1 = *(const bf16x8*)(sm + (bB ^ (ks << 5)));
      c00 = MFMA32(a0, b0, c00); c01 = MFMA32(a0, b1, c01);
      c10 = MFMA32(a1, b0, c10); c11 = MFMA32(a1, b1, c11);
    }
    res_epi(c00, res00, 0, qb0, imgbase, hi, sm, lsp, lbp);
    res_epi(c01, res01, 0, qb1, imgbase, hi, sm, lsp, lbp);
    res_epi(c10, res10, 1, qb0, imgbase, hi, sm, lsp, lbp);
    res_epi(c11, res11, 1, qb1, imgbase, hi, sm, lsp, lbp);
  }

  // ---- value head (f32) ----
  float part0 = 0.f, part1 = 0.f;
  #pragma unroll
  for (int rg = 0; rg < 4; ++rg){
    #pragma unroll
    for (int eh = 0; eh < 2; ++eh){
      unsigned pA0 = res00[rg*2+eh], pA1 = res01[rg*2+eh];
      unsigned pB0 = res10[rg*2+eh], pB1 = res11[rg*2+eh];
      int ob = rg*8 + hi*4 + eh*2;
      float w0 = vconv_w[ob],      w1 = vconv_w[ob+1];
      float w2 = vconv_w[32+ob],   w3 = vconv_w[32+ob+1];
      part0 += bf2f((unsigned short)(pA0 & 0xffffu))*w0 + bf2f((unsigned short)(pA0 >> 16))*w1
             + bf2f((unsigned short)(pB0 & 0xffffu))*w2 + bf2f((unsigned short)(pB0 >> 16))*w3;
      part1 += bf2f((unsigned short)(pA1 & 0xffffu))*w0 + bf2f((unsigned short)(pA1 >> 16))*w1
             + bf2f((unsigned short)(pB1 & 0xffffu))*w2 + bf2f((unsigned short)(pB1 >> 16))*w3;
    }
  }
  part0 += __shfl_xor(part0, 32);
  part1 += __shfl_xor(part1, 32);
  float vs = v_s[0], vb = v_b[0];
  float vv0 = vs*part0 + vb; vv0 = vv0 > 0.f ? vv0 : 0.f;
  float vv1 = vs*part1 + vb; vv1 = vv1 > 0.f ? vv1 : 0.f;
  float* vbuf = (float*)(sm + xinbase);
  vbuf[p0]  = vv0;
  vbuf[p1c] = vv1;

  float hidv[4];
  #pragma unroll
  for (int it = 0; it < 4; ++it){
    int jj = it*64 + lane;
    float a = vfc1_b[jj];
    for (int k = 0; k < 64; k += 4){
      float4v vv = *(const float4v*)(vbuf + k);
      a += vfc1_w[jj*64+k]*vv[0] + vfc1_w[jj*64+k+1]*vv[1]
         + vfc1_w[jj*64+k+2]*vv[2] + vfc1_w[jj*64+k+3]*vv[3];
    }
    hidv[it] = a > 0.f ? a : 0.f;
  }
  float tot = 0.f;
  #pragma unroll
  for (int it = 0; it < 4; ++it) tot += hidv[it]*vfc2_w[it*64 + lane];
  #pragma unroll
  for (int off = 32; off; off >>= 1) tot += __shfl_xor(tot, off);
  if (lane == 0) value_out[img] = tanhf(tot + vfc2_b[0]);
}

// ======================= gather / piece head =======================
__global__ __launch_bounds__(256) void gather_k(const unsigned short* __restrict__ act0,
                                                unsigned short* __restrict__ pvec,
                                                float* __restrict__ pid_out){
  int lane = threadIdx.x & 63, wave = threadIdx.x >> 6;
  int img = blockIdx.x*4 + wave;
  const unsigned short* arow = act0 + (size_t)img*4096;
  int myid = (int)bf2f(arow[lane*64 + 63]);
  int mypos = 0, mypres = 0;
  for (int p = 0; p < 32; ++p){
    unsigned long long m = __ballot(myid == (p+1));
    if (lane == p){ mypres = (m != 0ull); mypos = mypres ? (__ffsll(m) - 1) : 0; }
  }
  if (lane < 32){
    float v = mypres ? (float)(lane+1) : 0.f;
    #pragma unroll
    for (int s = 0; s < 8; ++s) pid_out[(size_t)img*256 + s*32 + lane] = v;
  }
  for (int p = 0; p < 32; ++p){
    int q  = __shfl(mypos, p);
    int pr = __shfl(mypres, p);
    unsigned short v = pr ? arow[q*64 + lane] : (unsigned short)0;
    pvec[(size_t)img*2048 + p*64 + lane] = v;
  }
}

// ======================= policy head GEMMs =======================
__global__ __launch_bounds__(256) void fc1_k(const unsigned short* __restrict__ pvec,
                                             const unsigned short* __restrict__ w,
                                             const float* __restrict__ bias,
                                             unsigned short* __restrict__ hid){
  int lane = threadIdx.x & 63, wave = threadIdx.x >> 6;
  int col = lane & 31, hi = lane >> 5;
  int wm = wave >> 1, wn = wave & 1;
  int m0 = blockIdx.x*128 + wm*64;
  int n0 = blockIdx.y*128 + wn*64;
  f32x16 a00 = {}, a01 = {}, a10 = {}, a11 = {};
  for (int k = 0; k < 2048; k += 16){
    bf16x8 A0 = *(const bf16x8*)(pvec + (size_t)(m0+col)*2048    + k + hi*8);
    bf16x8 A1 = *(const bf16x8*)(pvec + (size_t)(m0+32+col)*2048 + k + hi*8);
    bf16x8 B0 = *(const bf16x8*)(w + (size_t)(n0+col)*2048    + k + hi*8);
    bf16x8 B1 = *(const bf16x8*)(w + (size_t)(n0+32+col)*2048 + k + hi*8);
    a00 = MFMA32(A0, B0, a00); a01 = MFMA32(A0, B1, a01);
    a10 = MFMA32(A1, B0, a10); a11 = MFMA32(A1, B1, a11);
  }
  #pragma unroll
  for (int mt = 0; mt < 2; ++mt)
    #pragma unroll
    for (int nt = 0; nt < 2; ++nt){
      const f32x16& acc = mt == 0 ? (nt == 0 ? a00 : a01) : (nt == 0 ? a10 : a11);
      int jcol = n0 + nt*32 + col;
      float bj = bias[jcol];
      #pragma unroll
      for (int rg = 0; rg < 4; ++rg)
        #pragma unroll
        for (int e = 0; e < 4; ++e){
          int n = m0 + mt*32 + rg*8 + hi*4 + e;
          float v = acc[rg*4+e] + bj; v = v > 0.f ? v : 0.f;
          hid[(size_t)n*256 + jcol] = f2bf(v);
        }
    }
}

__global__ __launch_bounds__(256) void fc2_k(const unsigned short* __restrict__ hid,
                                             const unsigned short* __restrict__ w,
                                             const float* __restrict__ bias,
                                             float* __restrict__ pol){
  int lane = threadIdx.x & 63, wave = threadIdx.x >> 6;
  int col = lane & 31, hi = lane >> 5;
  int wm = wave >> 1, wn = wave & 1;
  int m0 = blockIdx.x*128 + wm*64;
  int n0 = blockIdx.y*128 + wn*64;
  f32x16 a00 = {}, a01 = {}, a10 = {}, a11 = {};
  for (int k = 0; k < 256; k += 16){
    bf16x8 A0 = *(const bf16x8*)(hid + (size_t)(m0+col)*256    + k + hi*8);
    bf16x8 A1 = *(const bf16x8*)(hid + (size_t)(m0+32+col)*256 + k + hi*8);
    bf16x8 B0 = *(const bf16x8*)(w + (size_t)(n0+col)*256    + k + hi*8);
    bf16x8 B1 = *(const bf16x8*)(w + (size_t)(n0+32+col)*256 + k + hi*8);
    a00 = MFMA32(A0, B0, a00); a01 = MFMA32(A0, B1, a01);
    a10 = MFMA32(A1, B0, a10); a11 = MFMA32(A1, B1, a11);
  }
  #pragma unroll
  for (int mt = 0; mt < 2; ++mt)
    #pragma unroll
    for (int nt = 0; nt < 2; ++nt){
      const f32x16& acc = mt == 0 ? (nt == 0 ? a00 : a01) : (nt == 0 ? a10 : a11);
      int jcol = n0 + nt*32 + col;
      if (jcol < 1700){
        float bj = bias[jcol];
        #pragma unroll
        for (int rg = 0; rg < 4; ++rg)
          #pragma unroll
          for (int e = 0; e < 4; ++e){
            int n = m0 + mt*32 + rg*8 + hi*4 + e;
            pol[(size_t)n*1700 + jcol] = acc[rg*4+e] + bj;
          }
      }
    }
}

// ======================= launch =======================
extern "C" void kernel_launch(void* const* d_in, const int* in_sizes, int n_in,
                              void* d_out, int out_size, void* d_ws, size_t ws_size,
                              hipStream_t stream){
  const float* x       = (const float*)d_in[0];
  const float* first_w = (const float*)d_in[1];
  const float* first_s = (const float*)d_in[2];
  const float* first_b = (const float*)d_in[3];
  const float* res_w   = (const float*)d_in[4];
  const float* res_s   = (const float*)d_in[5];
  const float* res_b   = (const float*)d_in[6];
  const float* last_w  = (const float*)d_in[7];
  const float* last_s  = (const float*)d_in[8];
  const float* last_b  = (const float*)d_in[9];
  const float* pfc1_w  = (const float*)d_in[10];
  const float* pfc1_b  = (const float*)d_in[11];
  const float* pfc2_w  = (const float*)d_in[12];
  const float* pfc2_b  = (const float*)d_in[13];
  const float* vconv_w = (const float*)d_in[14];
  const float* v_s     = (const float*)d_in[15];
  const float* v_b     = (const float*)d_in[16];
  const float* vfc1_w  = (const float*)d_in[17];
  const float* vfc1_b  = (const float*)d_in[18];
  const float* vfc2_w  = (const float*)d_in[19];
  const float* vfc2_b  = (const float*)d_in[20];
  unsigned short* ws = (unsigned short*)d_ws;
  float* out = (float*)d_out;

  prep_res_k <<<3136, 256, 0, stream>>>(res_w, ws);
  prep_misc_k<<<1024, 256, 0, stream>>>(first_w, last_w, pfc1_w, pfc2_w, ws);
  tower_k    <<<256, 256, 0, stream>>>(x, first_s, first_b, res_s, res_b, last_s, last_b,
                                       vconv_w, v_s, v_b, vfc1_w, vfc1_b, vfc2_w, vfc2_b,
                                       ws, ws + ACT0_OFF, out + VAL_OFF);
  gather_k   <<<256, 256, 0, stream>>>(ws + ACT0_OFF, ws + PV_OFF, out + PID_OFF);
  fc1_k      <<<dim3(8, 2), 256, 0, stream>>>(ws + PV_OFF, ws + P1_OFF, pfc1_b, ws + HID_OFF);
  fc2_k      <<<dim3(8, 14), 256, 0, stream>>>(ws + HID_OFF, ws + P2_OFF, pfc2_b, out);
}

// Round 3
// 2386.733 us; speedup vs baseline: 1.3132x; 1.3132x over previous
//
#include <hip/hip_runtime.h>

typedef __attribute__((ext_vector_type(8)))  short          bf16x8;
typedef __attribute__((ext_vector_type(16))) float          f32x16;
typedef __attribute__((ext_vector_type(8)))  unsigned int   u32x8;
typedef __attribute__((ext_vector_type(4)))  unsigned short ushort4v;
typedef __attribute__((ext_vector_type(4)))  float          float4v;

#define DEV static __device__ __forceinline__
#define MFMA32(A,B,C) __builtin_amdgcn_mfma_f32_32x32x16_bf16(A,B,C,0,0,0)

// ---- workspace element offsets (unsigned short elements) ----
// WRES: weight tile STREAM in exact consumption order:
//   for st in 0..6: 343 conv tiles (7 layers x 49 taps) + 1 last_w tile
//   = 2408 tiles x 4096 shorts (8KB) each, frag-major [frag(ks*2+mt)][lane][8]
#define NTILES   2408
#define WRES_OFF 0u           // 2408 * 4096                        = 9,863,168
#define FW_OFF   9863168u     // 49 taps * 2 frag * 64 lane * 8     =    50,176
#define P1_OFF   9913344u     // 256 * 2048                         =   524,288
#define P2_OFF   10437632u    // 1792 * 256 (padded rows)           =   458,752
#define ACT0_OFF 10896384u    // 1024 * 64p * 64c                   = 4,194,304
#define PV_OFF   15090688u    // 1024 * 32 * 64                     = 2,097,152
#define HID_OFF  17187840u    // 1024 * 256                         =   262,144
// total 17,449,984 ushorts = 34.9 MB

// ---- d_out offsets (floats) ----
#define VAL_OFF 1740800
#define PID_OFF 1741824

// ---- tower LDS map ----
#define SM_Z     57344      // 128B zero row (after 4 * 14336 act buffers)
#define SM_XIN   57472      // 4 * 3584 first-conv input staging
#define WBUF_OFF 71808      // 3 x 8192 weight-tile ring
#define SM_BYTES 96384

DEV float bf2f(unsigned short u){ union { unsigned int i; float f; } v; v.i = ((unsigned int)u) << 16; return v.f; }
DEV unsigned short f2bf(float f){
  union { float f; unsigned int i; } v; v.f = f;
  unsigned int x = v.i;
  return (unsigned short)((x + 0x7fffu + ((x >> 16) & 1u)) >> 16);  // RNE
}

// ======================= weight prep =======================
// res_w (7,7,64,64,7,7) f32 -> stream tile (L*49+t+L/7), frag-major:
// element (lane,j) of frag (ks*2+mt) = W[o = mt*32 + (lane&31)][c = ks*16 + (lane>>5)*8 + j]
__global__ void prep_res_k(const float* __restrict__ res_w, unsigned short* __restrict__ ws){
  __shared__ float buf[3136];
  int bx = blockIdx.x;             // L*64 + o
  int L = bx >> 6, o = bx & 63;
  const float* src = res_w + (size_t)bx * 3136;   // (o fixed): [c][dy][dx] contiguous
  for (int e = threadIdx.x; e < 3136; e += 256) buf[e] = src[e];
  __syncthreads();
  unsigned short* dst = ws + WRES_OFF;
  int mt = o >> 5, lrow = o & 31;
  int tilebase = L*49 + L/7;
  for (int e = threadIdx.x; e < 3136; e += 256){
    int t = e >> 6, c = e & 63;
    int ks = c >> 4, hi = (c >> 3) & 1, j = c & 7;
    int lane = hi*32 + lrow;
    dst[(size_t)(tilebase + t)*4096 + ((ks*2 + mt)*64 + lane)*8 + j] = f2bf(buf[c*49 + t]);
  }
}

// first_w -> fw[t][mt][lane][8] (K=16: c = (lane>>5)*8+j, 12 real + 4 zero)
// last_w  -> stream tile (st*344+343), frag-major
// pfc1/pfc2 cast (+pad)
__global__ void prep_misc_k(const float* __restrict__ first_w, const float* __restrict__ last_w,
                            const float* __restrict__ pfc1_w, const float* __restrict__ pfc2_w,
                            unsigned short* __restrict__ ws){
  const int n_fw = 49*1024, n_lw = 28672, n_p1 = 524288, n_p2 = 458752;
  const int total = n_fw + n_lw + n_p1 + n_p2;
  for (int d = blockIdx.x*256 + threadIdx.x; d < total; d += gridDim.x*256){
    if (d < n_fw){
      int t = d >> 10, r = d & 1023;
      int mt = r >> 9, lane = (r >> 3) & 63, j = r & 7;
      int o = mt*32 + (lane & 31);
      int c = ((lane >> 5) << 3) + j;
      float v = (o < 63 && c < 12) ? first_w[(o*12 + c)*49 + t] : 0.f;
      ws[FW_OFF + d] = f2bf(v);
    } else if (d < n_fw + n_lw){
      int e = d - n_fw;
      int st = e >> 12, r = e & 4095;
      int f = r >> 9, lane = (r >> 3) & 63, j = r & 7;
      int ks = f >> 1, mt = f & 1;
      int o = mt*32 + (lane & 31);
      int c = ks*16 + ((lane >> 5) << 3) + j;
      ws[WRES_OFF + (size_t)(st*344 + 343)*4096 + r] = f2bf(last_w[st*4096 + o*64 + c]);
    } else if (d < n_fw + n_lw + n_p1){
      int e = d - n_fw - n_lw; ws[P1_OFF + e] = f2bf(pfc1_w[e]);
    } else {
      int e = d - n_fw - n_lw - n_p1;
      int row = e >> 8, k = e & 255;
      ws[P2_OFF + e] = f2bf(row < 1700 ? pfc2_w[row*256 + k] : 0.f);
    }
  }
}

// ======================= tower =======================
DEV int baddr(int q, bool valid, int imgbase, int hi){
  int sz = (q & 7) << 4;
  int a = (q << 7) + ((imgbase + hi*16) ^ sz);
  return valid ? a : (SM_Z + hi*16);
}

// stage one 8KB weight tile: wave w DMAs frags 2w, 2w+1 (1KB each) into the ring
DEV void stage_tile(unsigned char* sm, const unsigned short* wstream, int s, int wave, int lane){
  const unsigned short* g = wstream + (size_t)s*4096 + wave*1024 + lane*8;
  unsigned char* l = sm + WBUF_OFF + (s % 3)*8192 + wave*2048;
  __builtin_amdgcn_global_load_lds((const __attribute__((address_space(1))) unsigned int*)g,
                                   (__attribute__((address_space(3))) unsigned int*)l, 16, 0, 0);
  __builtin_amdgcn_global_load_lds((const __attribute__((address_space(1))) unsigned int*)(g + 512),
                                   (__attribute__((address_space(3))) unsigned int*)(l + 1024), 16, 0, 0);
}

DEV void conv_epi(const f32x16& acc, int mt, int qb, int imgbase, int hi,
                  unsigned char* smp, const float* sp, const float* bp){
  int qw = qb + 3; int swzw = (qw & 7) << 4; int rowb = imgbase + (qw << 7);
  #pragma unroll
  for (int rg = 0; rg < 4; ++rg){
    int o0 = mt*32 + rg*8 + hi*4;
    unsigned short bb[4];
    #pragma unroll
    for (int e = 0; e < 4; ++e){
      float v = sp[o0+e]*acc[rg*4+e] + bp[o0+e];
      v = v > 0.f ? v : 0.f;
      bb[e] = f2bf(v);
    }
    int ob = mt*64 + rg*16 + hi*8;
    *(ushort4v*)(smp + rowb + (ob ^ swzw)) = ushort4v{bb[0],bb[1],bb[2],bb[3]};
  }
}

DEV void res_epi(const f32x16& acc, u32x8& res, int mt, int qb, int imgbase, int hi,
                 unsigned char* smp, const float* lsp, const float* lbp){
  int qw = qb + 3; int swzw = (qw & 7) << 4; int rowb = imgbase + (qw << 7);
  #pragma unroll
  for (int rg = 0; rg < 4; ++rg){
    int o0 = mt*32 + rg*8 + hi*4;
    unsigned short bb[4];
    #pragma unroll
    for (int e = 0; e < 4; ++e){
      unsigned pr = res[rg*2 + (e>>1)];
      float rv = bf2f((unsigned short)((e & 1) ? (pr >> 16) : (pr & 0xffffu)));
      float v = lsp[o0+e]*acc[rg*4+e] + lbp[o0+e] + rv;
      v = v > 0.f ? v : 0.f;
      bb[e] = f2bf(v);
    }
    res[rg*2]   = (unsigned)bb[0] | ((unsigned)bb[1] << 16);
    res[rg*2+1] = (unsigned)bb[2] | ((unsigned)bb[3] << 16);
    int ob = mt*64 + rg*16 + hi*8;
    *(ushort4v*)(smp + rowb + (ob ^ swzw)) = ushort4v{bb[0],bb[1],bb[2],bb[3]};
  }
}

DEV void first_epi(const f32x16& acc, u32x8& res, int mt, int qb, int p, float idsv,
                   int img, int imgbase, int hi, unsigned char* smp,
                   const float* fsp, const float* fbp, unsigned short* act0){
  int qw = qb + 3; int swzw = (qw & 7) << 4; int rowb = imgbase + (qw << 7);
  #pragma unroll
  for (int rg = 0; rg < 4; ++rg){
    int o0 = mt*32 + rg*8 + hi*4;
    unsigned short bb[4];
    #pragma unroll
    for (int e = 0; e < 4; ++e){
      int o = o0 + e;
      int oc = o < 63 ? o : 62;          // avoid OOB load of 63-entry arrays
      float v = fsp[oc]*acc[rg*4+e] + fbp[oc];
      v = v > 0.f ? v : 0.f;
      if (o == 63) v = idsv;             // ids channel, no bn/relu
      bb[e] = f2bf(v);
    }
    res[rg*2]   = (unsigned)bb[0] | ((unsigned)bb[1] << 16);
    res[rg*2+1] = (unsigned)bb[2] | ((unsigned)bb[3] << 16);
    int ob = mt*64 + rg*16 + hi*8;
    *(ushort4v*)(smp + rowb + (ob ^ swzw)) = ushort4v{bb[0],bb[1],bb[2],bb[3]};
    *(ushort4v*)(act0 + (size_t)img*4096 + p*64 + o0) = ushort4v{bb[0],bb[1],bb[2],bb[3]};
  }
}

__global__ __launch_bounds__(256, 1) void tower_k(
    const float* __restrict__ x,
    const float* __restrict__ first_s, const float* __restrict__ first_b,
    const float* __restrict__ res_s,   const float* __restrict__ res_b,
    const float* __restrict__ last_s,  const float* __restrict__ last_b,
    const float* __restrict__ vconv_w, const float* __restrict__ v_s, const float* __restrict__ v_b,
    const float* __restrict__ vfc1_w,  const float* __restrict__ vfc1_b,
    const float* __restrict__ vfc2_w,  const float* __restrict__ vfc2_b,
    const unsigned short* ws_r, unsigned short* act0, float* value_out)
{
  __shared__ unsigned char sm[SM_BYTES];
  int tid = threadIdx.x, lane = tid & 63, wave = tid >> 6;
  int img = blockIdx.x * 4 + wave;

  for (int i = tid*16; i < SM_BYTES; i += 256*16) *(float4v*)(sm + i) = float4v{0,0,0,0};
  __syncthreads();

  int col = lane & 31, hi = lane >> 5;
  int imgbase = wave * 14336;
  int xinbase = SM_XIN + wave * 3584;

  int p0 = col, p1c = 32 + col;
  int y0 = p0 >> 3, y1 = p1c >> 3;
  int qb0 = y0*14 + (p0 & 7), qb1 = y1*14 + (p1c & 7);

  const unsigned short* wstream = ws_r + WRES_OFF;
  // start the weight-tile DMA pipeline before the first conv so it overlaps
  stage_tile(sm, wstream, 0, wave, lane);
  stage_tile(sm, wstream, 1, wave, lane);

  // ---- stage x into padded xin (bf16), channels 0..11 ----
  const float* xim = x + (size_t)img * 832;
  {
    int q = (lane >> 3)*14 + (lane & 7) + 3;
    for (int c = 0; c < 12; ++c){
      *(unsigned short*)(sm + xinbase + q*32 + c*2) = f2bf(xim[c*64 + lane]);
    }
  }
  float ids0 = xim[768 + p0];
  float ids1 = xim[768 + p1c];

  // ---- first conv (K=16: 12 real + 4 zero channels) ----
  f32x16 f00 = {}, f01 = {}, f10 = {}, f11 = {};
  const unsigned short* fw = ws_r + FW_OFF;
  #pragma unroll
  for (int dy = 0; dy < 7; ++dy){
    bool v0 = (unsigned)(y0 + dy - 3) < 8u;
    bool v1 = (unsigned)(y1 + dy - 3) < 8u;
    int tq = (dy-3)*14;
    #pragma unroll
    for (int dx = 0; dx < 7; ++dx){
      int t = dy*7 + dx;
      bf16x8 a0 = *(const bf16x8*)(fw + t*1024 +       lane*8);
      bf16x8 a1 = *(const bf16x8*)(fw + t*1024 + 512 + lane*8);
      int q0 = qb0 + tq + dx, q1 = qb1 + tq + dx;
      int b0a = v0 ? (xinbase + (q0 << 5) + hi*16) : (SM_Z + hi*16);
      int b1a = v1 ? (xinbase + (q1 << 5) + hi*16) : (SM_Z + hi*16);
      bf16x8 bb0 = *(const bf16x8*)(sm + b0a);
      bf16x8 bb1 = *(const bf16x8*)(sm + b1a);
      f00 = MFMA32(a0, bb0, f00);
      f01 = MFMA32(a0, bb1, f01);
      f10 = MFMA32(a1, bb0, f10);
      f11 = MFMA32(a1, bb1, f11);
    }
  }
  u32x8 res00, res01, res10, res11;
  first_epi(f00, res00, 0, qb0, p0,  ids0, img, imgbase, hi, sm, first_s, first_b, act0);
  first_epi(f01, res01, 0, qb1, p1c, ids1, img, imgbase, hi, sm, first_s, first_b, act0);
  first_epi(f10, res10, 1, qb0, p0,  ids0, img, imgbase, hi, sm, first_s, first_b, act0);
  first_epi(f11, res11, 1, qb1, p1c, ids1, img, imgbase, hi, sm, first_s, first_b, act0);

  // ---- residual tower: staged weight-tile stream ----
  const f32x16 zf = {};
  f32x16 c00 = zf, c01 = zf, c10 = zf, c11 = zf;
  int dy = 0, dx = 0, L = 0, st = 0;
  for (int s = 0; s < NTILES; ++s){
    if (s + 2 < NTILES) stage_tile(sm, wstream, s + 2, wave, lane);
    // counted waits: my 4 newest stage loads (tiles s+1, s+2) may stay in flight;
    // tile s's 2 loads are complete.  (never vmcnt(0) in steady state)
    if (s < NTILES - 2)       asm volatile("s_waitcnt vmcnt(4)" ::: "memory");
    else if (s == NTILES - 2) asm volatile("s_waitcnt vmcnt(2)" ::: "memory");
    else                      asm volatile("s_waitcnt vmcnt(0)" ::: "memory");
    __builtin_amdgcn_s_barrier();
    asm volatile("" ::: "memory");
    const unsigned short* wb = (const unsigned short*)(sm + WBUF_OFF + (s % 3)*8192);
    int r = s - st*344;
    if (r < 343){
      // conv tap (dy,dx) of layer L
      bool v0 = (unsigned)(y0 + dy - 3) < 8u;
      bool v1 = (unsigned)(y1 + dy - 3) < 8u;
      int tq = (dy - 3)*14 + dx;
      bf16x8 a0k[4], a1k[4];
      #pragma unroll
      for (int ks = 0; ks < 4; ++ks){
        a0k[ks] = *(const bf16x8*)(wb + (ks*2    )*512 + lane*8);
        a1k[ks] = *(const bf16x8*)(wb + (ks*2 + 1)*512 + lane*8);
      }
      int b0 = baddr(qb0 + tq, v0, imgbase, hi);
      int b1 = baddr(qb1 + tq, v1, imgbase, hi);
      #pragma unroll
      for (int ks = 0; ks < 4; ++ks){
        bf16x8 bf0 = *(const bf16x8*)(sm + (b0 ^ (ks << 5)));
        bf16x8 bf1 = *(const bf16x8*)(sm + (b1 ^ (ks << 5)));
        c00 = MFMA32(a0k[ks], bf0, c00);
        c01 = MFMA32(a0k[ks], bf1, c01);
        c10 = MFMA32(a1k[ks], bf0, c10);
        c11 = MFMA32(a1k[ks], bf1, c11);
      }
      ++dx;
      if (dx == 7){ dx = 0; ++dy; }
      if (dy == 7){
        dy = 0;
        const float* sp = res_s + L*64;
        const float* bp = res_b + L*64;
        conv_epi(c00, 0, qb0, imgbase, hi, sm, sp, bp);
        conv_epi(c01, 0, qb1, imgbase, hi, sm, sp, bp);
        conv_epi(c10, 1, qb0, imgbase, hi, sm, sp, bp);
        conv_epi(c11, 1, qb1, imgbase, hi, sm, sp, bp);
        c00 = zf; c01 = zf; c10 = zf; c11 = zf;
        ++L;
      }
    } else {
      // 1x1 (last_w) + bn + residual + relu
      const float* lsp = last_s + st*64;
      const float* lbp = last_b + st*64;
      f32x16 d00 = zf, d01 = zf, d10 = zf, d11 = zf;
      int bA = baddr(qb0 + 3, true, imgbase, hi);
      int bB = baddr(qb1 + 3, true, imgbase, hi);
      #pragma unroll
      for (int ks = 0; ks < 4; ++ks){
        bf16x8 a0 = *(const bf16x8*)(wb + (ks*2    )*512 + lane*8);
        bf16x8 a1 = *(const bf16x8*)(wb + (ks*2 + 1)*512 + lane*8);
        bf16x8 b0 = *(const bf16x8*)(sm + (bA ^ (ks << 5)));
        bf16x8 b1 = *(const bf16x8*)(sm + (bB ^ (ks << 5)));
        d00 = MFMA32(a0, b0, d00); d01 = MFMA32(a0, b1, d01);
        d10 = MFMA32(a1, b0, d10); d11 = MFMA32(a1, b1, d11);
      }
      res_epi(d00, res00, 0, qb0, imgbase, hi, sm, lsp, lbp);
      res_epi(d01, res01, 0, qb1, imgbase, hi, sm, lsp, lbp);
      res_epi(d10, res10, 1, qb0, imgbase, hi, sm, lsp, lbp);
      res_epi(d11, res11, 1, qb1, imgbase, hi, sm, lsp, lbp);
      ++st;
    }
    __builtin_amdgcn_s_barrier();
    asm volatile("" ::: "memory");
  }

  // ---- value head (f32) ----
  float part0 = 0.f, part1 = 0.f;
  #pragma unroll
  for (int rg = 0; rg < 4; ++rg){
    #pragma unroll
    for (int eh = 0; eh < 2; ++eh){
      unsigned pA0 = res00[rg*2+eh], pA1 = res01[rg*2+eh];
      unsigned pB0 = res10[rg*2+eh], pB1 = res11[rg*2+eh];
      int ob = rg*8 + hi*4 + eh*2;
      float w0 = vconv_w[ob],      w1 = vconv_w[ob+1];
      float w2 = vconv_w[32+ob],   w3 = vconv_w[32+ob+1];
      part0 += bf2f((unsigned short)(pA0 & 0xffffu))*w0 + bf2f((unsigned short)(pA0 >> 16))*w1
             + bf2f((unsigned short)(pB0 & 0xffffu))*w2 + bf2f((unsigned short)(pB0 >> 16))*w3;
      part1 += bf2f((unsigned short)(pA1 & 0xffffu))*w0 + bf2f((unsigned short)(pA1 >> 16))*w1
             + bf2f((unsigned short)(pB1 & 0xffffu))*w2 + bf2f((unsigned short)(pB1 >> 16))*w3;
    }
  }
  part0 += __shfl_xor(part0, 32);
  part1 += __shfl_xor(part1, 32);
  float vs = v_s[0], vb = v_b[0];
  float vv0 = vs*part0 + vb; vv0 = vv0 > 0.f ? vv0 : 0.f;
  float vv1 = vs*part1 + vb; vv1 = vv1 > 0.f ? vv1 : 0.f;
  float* vbuf = (float*)(sm + xinbase);
  vbuf[p0]  = vv0;
  vbuf[p1c] = vv1;

  float hidv[4];
  #pragma unroll
  for (int it = 0; it < 4; ++it){
    int jj = it*64 + lane;
    float a = vfc1_b[jj];
    for (int k = 0; k < 64; k += 4){
      float4v vv = *(const float4v*)(vbuf + k);
      a += vfc1_w[jj*64+k]*vv[0] + vfc1_w[jj*64+k+1]*vv[1]
         + vfc1_w[jj*64+k+2]*vv[2] + vfc1_w[jj*64+k+3]*vv[3];
    }
    hidv[it] = a > 0.f ? a : 0.f;
  }
  float tot = 0.f;
  #pragma unroll
  for (int it = 0; it < 4; ++it) tot += hidv[it]*vfc2_w[it*64 + lane];
  #pragma unroll
  for (int off = 32; off; off >>= 1) tot += __shfl_xor(tot, off);
  if (lane == 0) value_out[img] = tanhf(tot + vfc2_b[0]);
}

// ======================= gather / piece head =======================
__global__ __launch_bounds__(256) void gather_k(const unsigned short* __restrict__ act0,
                                                unsigned short* __restrict__ pvec,
                                                float* __restrict__ pid_out){
  int lane = threadIdx.x & 63, wave = threadIdx.x >> 6;
  int img = blockIdx.x*4 + wave;
  const unsigned short* arow = act0 + (size_t)img*4096;
  int myid = (int)bf2f(arow[lane*64 + 63]);
  int mypos = 0, mypres = 0;
  for (int p = 0; p < 32; ++p){
    unsigned long long m = __ballot(myid == (p+1));
    if (lane == p){ mypres = (m != 0ull); mypos = mypres ? (__ffsll(m) - 1) : 0; }
  }
  if (lane < 32){
    float v = mypres ? (float)(lane+1) : 0.f;
    #pragma unroll
    for (int s = 0; s < 8; ++s) pid_out[(size_t)img*256 + s*32 + lane] = v;
  }
  for (int p = 0; p < 32; ++p){
    int q  = __shfl(mypos, p);
    int pr = __shfl(mypres, p);
    unsigned short v = pr ? arow[q*64 + lane] : (unsigned short)0;
    pvec[(size_t)img*2048 + p*64 + lane] = v;
  }
}

// ======================= policy head GEMMs =======================
__global__ __launch_bounds__(256) void fc1_k(const unsigned short* __restrict__ pvec,
                                             const unsigned short* __restrict__ w,
                                             const float* __restrict__ bias,
                                             unsigned short* __restrict__ hid){
  int lane = threadIdx.x & 63, wave = threadIdx.x >> 6;
  int col = lane & 31, hi = lane >> 5;
  int wm = wave >> 1, wn = wave & 1;
  int m0 = blockIdx.x*128 + wm*64;
  int n0 = blockIdx.y*128 + wn*64;
  f32x16 a00 = {}, a01 = {}, a10 = {}, a11 = {};
  for (int k = 0; k < 2048; k += 16){
    bf16x8 A0 = *(const bf16x8*)(pvec + (size_t)(m0+col)*2048    + k + hi*8);
    bf16x8 A1 = *(const bf16x8*)(pvec + (size_t)(m0+32+col)*2048 + k + hi*8);
    bf16x8 B0 = *(const bf16x8*)(w + (size_t)(n0+col)*2048    + k + hi*8);
    bf16x8 B1 = *(const bf16x8*)(w + (size_t)(n0+32+col)*2048 + k + hi*8);
    a00 = MFMA32(A0, B0, a00); a01 = MFMA32(A0, B1, a01);
    a10 = MFMA32(A1, B0, a10); a11 = MFMA32(A1, B1, a11);
  }
  #pragma unroll
  for (int mt = 0; mt < 2; ++mt)
    #pragma unroll
    for (int nt = 0; nt < 2; ++nt){
      const f32x16& acc = mt == 0 ? (nt == 0 ? a00 : a01) : (nt == 0 ? a10 : a11);
      int jcol = n0 + nt*32 + col;
      float bj = bias[jcol];
      #pragma unroll
      for (int rg = 0; rg < 4; ++rg)
        #pragma unroll
        for (int e = 0; e < 4; ++e){
          int n = m0 + mt*32 + rg*8 + hi*4 + e;
          float v = acc[rg*4+e] + bj; v = v > 0.f ? v : 0.f;
          hid[(size_t)n*256 + jcol] = f2bf(v);
        }
    }
}

__global__ __launch_bounds__(256) void fc2_k(const unsigned short* __restrict__ hid,
                                             const unsigned short* __restrict__ w,
                                             const float* __restrict__ bias,
                                             float* __restrict__ pol){
  int lane = threadIdx.x & 63, wave = threadIdx.x >> 6;
  int col = lane & 31, hi = lane >> 5;
  int wm = wave >> 1, wn = wave & 1;
  int m0 = blockIdx.x*128 + wm*64;
  int n0 = blockIdx.y*128 + wn*64;
  f32x16 a00 = {}, a01 = {}, a10 = {}, a11 = {};
  for (int k = 0; k < 256; k += 16){
    bf16x8 A0 = *(const bf16x8*)(hid + (size_t)(m0+col)*256    + k + hi*8);
    bf16x8 A1 = *(const bf16x8*)(hid + (size_t)(m0+32+col)*256 + k + hi*8);
    bf16x8 B0 = *(const bf16x8*)(w + (size_t)(n0+col)*256    + k + hi*8);
    bf16x8 B1 = *(const bf16x8*)(w + (size_t)(n0+32+col)*256 + k + hi*8);
    a00 = MFMA32(A0, B0, a00); a01 = MFMA32(A0, B1, a01);
    a10 = MFMA32(A1, B0, a10); a11 = MFMA32(A1, B1, a11);
  }
  #pragma unroll
  for (int mt = 0; mt < 2; ++mt)
    #pragma unroll
    for (int nt = 0; nt < 2; ++nt){
      const f32x16& acc = mt == 0 ? (nt == 0 ? a00 : a01) : (nt == 0 ? a10 : a11);
      int jcol = n0 + nt*32 + col;
      if (jcol < 1700){
        float bj = bias[jcol];
        #pragma unroll
        for (int rg = 0; rg < 4; ++rg)
          #pragma unroll
          for (int e = 0; e < 4; ++e){
            int n = m0 + mt*32 + rg*8 + hi*4 + e;
            pol[(size_t)n*1700 + jcol] = acc[rg*4+e] + bj;
          }
      }
    }
}

// ======================= launch =======================
extern "C" void kernel_launch(void* const* d_in, const int* in_sizes, int n_in,
                              void* d_out, int out_size, void* d_ws, size_t ws_size,
                              hipStream_t stream){
  const float* x       = (const float*)d_in[0];
  const float* first_w = (const float*)d_in[1];
  const float* first_s = (const float*)d_in[2];
  const float* first_b = (const float*)d_in[3];
  const float* res_w   = (const float*)d_in[4];
  const float* res_s   = (const float*)d_in[5];
  const float* res_b   = (const float*)d_in[6];
  const float* last_w  = (const float*)d_in[7];
  const float* last_s  = (const float*)d_in[8];
  const float* last_b  = (const float*)d_in[9];
  const float* pfc1_w  = (const float*)d_in[10];
  const float* pfc1_b  = (const float*)d_in[11];
  const float* pfc2_w  = (const float*)d_in[12];
  const float* pfc2_b  = (const float*)d_in[13];
  const float* vconv_w = (const float*)d_in[14];
  const float* v_s     = (const float*)d_in[15];
  const float* v_b     = (const float*)d_in[16];
  const float* vfc1_w  = (const float*)d_in[17];
  const float* vfc1_b  = (const float*)d_in[18];
  const float* vfc2_w  = (const float*)d_in[19];
  const float* vfc2_b  = (const float*)d_in[20];
  unsigned short* ws = (unsigned short*)d_ws;
  float* out = (float*)d_out;

  prep_res_k <<<3136, 256, 0, stream>>>(res_w, ws);
  prep_misc_k<<<1024, 256, 0, stream>>>(first_w, last_w, pfc1_w, pfc2_w, ws);
  tower_k    <<<256, 256, 0, stream>>>(x, first_s, first_b, res_s, res_b, last_s, last_b,
                                       vconv_w, v_s, v_b, vfc1_w, vfc1_b, vfc2_w, vfc2_b,
                                       ws, ws + ACT0_OFF, out + VAL_OFF);
  gather_k   <<<256, 256, 0, stream>>>(ws + ACT0_OFF, ws + PV_OFF, out + PID_OFF);
  fc1_k      <<<dim3(8, 2), 256, 0, stream>>>(ws + PV_OFF, ws + P1_OFF, pfc1_b, ws + HID_OFF);
  fc2_k      <<<dim3(8, 14), 256, 0, stream>>>(ws + HID_OFF, ws + P2_OFF, pfc2_b, out);
}

// Round 4
// 1700.712 us; speedup vs baseline: 1.8429x; 1.4034x over previous
//
#include <hip/hip_runtime.h>

typedef __attribute__((ext_vector_type(8)))  short          bf16x8;
typedef __attribute__((ext_vector_type(16))) float          f32x16;
typedef __attribute__((ext_vector_type(8)))  unsigned int   u32x8;
typedef __attribute__((ext_vector_type(4)))  unsigned short ushort4v;
typedef __attribute__((ext_vector_type(4)))  float          float4v;

#define DEV static __device__ __forceinline__
#define MFMA32(A,B,C) __builtin_amdgcn_mfma_f32_32x32x16_bf16(A,B,C,0,0,0)

// ---- workspace element offsets (unsigned short elements) ----
// WRES: weight tile STREAM in exact consumption order:
//   for st in 0..6: 343 conv tiles (7 layers x 49 taps) + 1 last_w tile
//   = 2408 tiles x 4096 shorts (8KB) each, frag-major [frag(ks*2+mt)][lane][8]
#define NTILES   2408
#define WRES_OFF 0u           // 2408 * 4096                        = 9,863,168
#define FW_OFF   9863168u     // 49 taps * 2 frag * 64 lane * 8     =    50,176
#define P1_OFF   9913344u     // 256 * 2048                         =   524,288
#define P2_OFF   10437632u    // 1792 * 256 (padded rows)           =   458,752
#define ACT0_OFF 10896384u    // 1024 * 64p * 64c                   = 4,194,304
#define PV_OFF   15090688u    // 1024 * 32 * 64                     = 2,097,152
#define HID_OFF  17187840u    // 1024 * 256                         =   262,144
// total 17,449,984 ushorts = 34.9 MB

// ---- d_out offsets (floats) ----
#define VAL_OFF 1740800
#define PID_OFF 1741824

// ---- tower LDS map ----
// acts: 4 img x 64 rows x 128B (unpadded, XOR-swizzled)  = 32768
// zero row 128B; ring 3 x 8192 (xin + value bufs overlay the ring)
#define SM_Z     32768
#define WBUF_OFF 32896
#define SM_BYTES 57472

DEV float bf2f(unsigned short u){ union { unsigned int i; float f; } v; v.i = ((unsigned int)u) << 16; return v.f; }
DEV unsigned short f2bf(float f){
  union { float f; unsigned int i; } v; v.f = f;
  unsigned int x = v.i;
  return (unsigned short)((x + 0x7fffu + ((x >> 16) & 1u)) >> 16);  // RNE
}

// ======================= weight prep =======================
// res_w (7,7,64,64,7,7) f32 -> stream tile (L*49+t+L/7), frag-major:
// element (lane,j) of frag (ks*2+mt) = W[o = mt*32 + (lane&31)][c = ks*16 + (lane>>5)*8 + j]
__global__ void prep_res_k(const float* __restrict__ res_w, unsigned short* __restrict__ ws){
  __shared__ float buf[3136];
  int bx = blockIdx.x;             // L*64 + o
  int L = bx >> 6, o = bx & 63;
  const float* src = res_w + (size_t)bx * 3136;   // (o fixed): [c][dy][dx] contiguous
  for (int e = threadIdx.x; e < 3136; e += 256) buf[e] = src[e];
  __syncthreads();
  unsigned short* dst = ws + WRES_OFF;
  int mt = o >> 5, lrow = o & 31;
  int tilebase = L*49 + L/7;
  for (int e = threadIdx.x; e < 3136; e += 256){
    int t = e >> 6, c = e & 63;
    int ks = c >> 4, hi = (c >> 3) & 1, j = c & 7;
    int lane = hi*32 + lrow;
    dst[(size_t)(tilebase + t)*4096 + ((ks*2 + mt)*64 + lane)*8 + j] = f2bf(buf[c*49 + t]);
  }
}

// first_w -> fw[t][mt][lane][8] (K=16: c = (lane>>5)*8+j, 12 real + 4 zero)
// last_w  -> stream tile (st*344+343), frag-major
// pfc1/pfc2 cast (+pad)
__global__ void prep_misc_k(const float* __restrict__ first_w, const float* __restrict__ last_w,
                            const float* __restrict__ pfc1_w, const float* __restrict__ pfc2_w,
                            unsigned short* __restrict__ ws){
  const int n_fw = 49*1024, n_lw = 28672, n_p1 = 524288, n_p2 = 458752;
  const int total = n_fw + n_lw + n_p1 + n_p2;
  for (int d = blockIdx.x*256 + threadIdx.x; d < total; d += gridDim.x*256){
    if (d < n_fw){
      int t = d >> 10, r = d & 1023;
      int mt = r >> 9, lane = (r >> 3) & 63, j = r & 7;
      int o = mt*32 + (lane & 31);
      int c = ((lane >> 5) << 3) + j;
      float v = (o < 63 && c < 12) ? first_w[(o*12 + c)*49 + t] : 0.f;
      ws[FW_OFF + d] = f2bf(v);
    } else if (d < n_fw + n_lw){
      int e = d - n_fw;
      int st = e >> 12, r = e & 4095;
      int f = r >> 9, lane = (r >> 3) & 63, j = r & 7;
      int ks = f >> 1, mt = f & 1;
      int o = mt*32 + (lane & 31);
      int c = ks*16 + ((lane >> 5) << 3) + j;
      ws[WRES_OFF + (size_t)(st*344 + 343)*4096 + r] = f2bf(last_w[st*4096 + o*64 + c]);
    } else if (d < n_fw + n_lw + n_p1){
      int e = d - n_fw - n_lw; ws[P1_OFF + e] = f2bf(pfc1_w[e]);
    } else {
      int e = d - n_fw - n_lw - n_p1;
      int row = e >> 8, k = e & 255;
      ws[P2_OFF + e] = f2bf(row < 1700 ? pfc2_w[row*256 + k] : 0.f);
    }
  }
}

// ======================= tower =======================
// act row p (0..63), 128B channels, slot-swizzled by (p&7)<<4
DEV int baddr(int q, bool valid, int imgbase, int hi){
  int sz = (q & 7) << 4;
  int a = (q << 7) + ((imgbase + hi*16) ^ sz);
  return valid ? a : (SM_Z + hi*16);
}

// stage one 8KB weight tile: wave w DMAs frag w (1KB) into the ring
DEV void stage_tile(unsigned char* sm, const unsigned short* wstream, int s, int wave, int lane){
  const unsigned short* g = wstream + (size_t)s*4096 + wave*512 + lane*8;
  unsigned char* l = sm + WBUF_OFF + (s % 3)*8192 + wave*1024;
  __builtin_amdgcn_global_load_lds((const __attribute__((address_space(1))) unsigned int*)g,
                                   (__attribute__((address_space(3))) unsigned int*)l, 16, 0, 0);
}

DEV void conv_epi(const f32x16& acc, int mt, int p, int imgbase, int hi,
                  unsigned char* smp, const float* sp, const float* bp){
  int swzw = (p & 7) << 4; int rowb = imgbase + (p << 7);
  #pragma unroll
  for (int rg = 0; rg < 4; ++rg){
    int o0 = mt*32 + rg*8 + hi*4;
    unsigned short bb[4];
    #pragma unroll
    for (int e = 0; e < 4; ++e){
      float v = sp[o0+e]*acc[rg*4+e] + bp[o0+e];
      v = v > 0.f ? v : 0.f;
      bb[e] = f2bf(v);
    }
    int ob = mt*64 + rg*16 + hi*8;
    *(ushort4v*)(smp + rowb + (ob ^ swzw)) = ushort4v{bb[0],bb[1],bb[2],bb[3]};
  }
}

DEV void res_epi(const f32x16& acc, u32x8& res, int mt, int p, int imgbase, int hi,
                 unsigned char* smp, const float* lsp, const float* lbp){
  int swzw = (p & 7) << 4; int rowb = imgbase + (p << 7);
  #pragma unroll
  for (int rg = 0; rg < 4; ++rg){
    int o0 = mt*32 + rg*8 + hi*4;
    unsigned short bb[4];
    #pragma unroll
    for (int e = 0; e < 4; ++e){
      unsigned pr = res[rg*2 + (e>>1)];
      float rv = bf2f((unsigned short)((e & 1) ? (pr >> 16) : (pr & 0xffffu)));
      float v = lsp[o0+e]*acc[rg*4+e] + lbp[o0+e] + rv;
      v = v > 0.f ? v : 0.f;
      bb[e] = f2bf(v);
    }
    res[rg*2]   = (unsigned)bb[0] | ((unsigned)bb[1] << 16);
    res[rg*2+1] = (unsigned)bb[2] | ((unsigned)bb[3] << 16);
    int ob = mt*64 + rg*16 + hi*8;
    *(ushort4v*)(smp + rowb + (ob ^ swzw)) = ushort4v{bb[0],bb[1],bb[2],bb[3]};
  }
}

DEV void first_epi(const f32x16& acc, u32x8& res, int mt, int p, float idsv,
                   int img, int imgbase, int hi, unsigned char* smp,
                   const float* fsp, const float* fbp, unsigned short* act0){
  int swzw = (p & 7) << 4; int rowb = imgbase + (p << 7);
  #pragma unroll
  for (int rg = 0; rg < 4; ++rg){
    int o0 = mt*32 + rg*8 + hi*4;
    unsigned short bb[4];
    #pragma unroll
    for (int e = 0; e < 4; ++e){
      int o = o0 + e;
      int oc = o < 63 ? o : 62;          // avoid OOB load of 63-entry arrays
      float v = fsp[oc]*acc[rg*4+e] + fbp[oc];
      v = v > 0.f ? v : 0.f;
      if (o == 63) v = idsv;             // ids channel, no bn/relu
      bb[e] = f2bf(v);
    }
    res[rg*2]   = (unsigned)bb[0] | ((unsigned)bb[1] << 16);
    res[rg*2+1] = (unsigned)bb[2] | ((unsigned)bb[3] << 16);
    int ob = mt*64 + rg*16 + hi*8;
    *(ushort4v*)(smp + rowb + (ob ^ swzw)) = ushort4v{bb[0],bb[1],bb[2],bb[3]};
    *(ushort4v*)(act0 + (size_t)img*4096 + p*64 + o0) = ushort4v{bb[0],bb[1],bb[2],bb[3]};
  }
}

__global__ __launch_bounds__(512, 1) void tower_k(
    const float* __restrict__ x,
    const float* __restrict__ first_s, const float* __restrict__ first_b,
    const float* __restrict__ res_s,   const float* __restrict__ res_b,
    const float* __restrict__ last_s,  const float* __restrict__ last_b,
    const float* __restrict__ vconv_w, const float* __restrict__ v_s, const float* __restrict__ v_b,
    const float* __restrict__ vfc1_w,  const float* __restrict__ vfc1_b,
    const float* __restrict__ vfc2_w,  const float* __restrict__ vfc2_b,
    const unsigned short* ws_r, unsigned short* act0, float* value_out)
{
  __shared__ unsigned char sm[SM_BYTES];
  int tid = threadIdx.x, lane = tid & 63, wave = tid >> 6;
  int imgi = wave & 3, sub = wave >> 2;     // 2 waves (sub=0,1) per image
  int img = blockIdx.x * 4 + imgi;

  for (int i = tid*16; i < SM_BYTES; i += 512*16) *(float4v*)(sm + i) = float4v{0,0,0,0};
  __syncthreads();

  int col = lane & 31, hi = lane >> 5;
  int imgbase = imgi * 8192;
  int xinbase = WBUF_OFF + imgi * 3584;     // overlays ring (free until tower loop)

  int p0 = col, p1 = 32 + col;
  int y0 = p0 >> 3, x0v = p0 & 7, y1 = p1 >> 3, x1v = p1 & 7;

  const unsigned short* wstream = ws_r + WRES_OFF;
  const float* xim = x + (size_t)img * 832;
  if (sub == 0){
    int q = (lane >> 3)*14 + (lane & 7) + 3;
    for (int c = 0; c < 12; ++c)
      *(unsigned short*)(sm + xinbase + q*32 + c*2) = f2bf(xim[c*64 + lane]);
  }
  float ids0 = xim[768 + p0];
  float ids1 = xim[768 + p1];
  __syncthreads();

  // ---- first conv: sub computes channel-half mt=sub, both col groups ----
  f32x16 f0 = {}, f1 = {};
  const unsigned short* fw = ws_r + FW_OFF;
  int qb0x = y0*14 + x0v, qb1x = y1*14 + x1v;
  #pragma unroll
  for (int dy = 0; dy < 7; ++dy){
    bool v0 = (unsigned)(y0 + dy - 3) < 8u;
    bool v1 = (unsigned)(y1 + dy - 3) < 8u;
    int tq = (dy-3)*14;
    #pragma unroll
    for (int dx = 0; dx < 7; ++dx){
      int t = dy*7 + dx;
      bf16x8 a = *(const bf16x8*)(fw + t*1024 + sub*512 + lane*8);
      int q0 = qb0x + tq + dx, q1 = qb1x + tq + dx;
      int b0a = v0 ? (xinbase + q0*32 + hi*16) : (SM_Z + hi*16);
      int b1a = v1 ? (xinbase + q1*32 + hi*16) : (SM_Z + hi*16);
      bf16x8 bb0 = *(const bf16x8*)(sm + b0a);
      bf16x8 bb1 = *(const bf16x8*)(sm + b1a);
      f0 = MFMA32(a, bb0, f0);
      f1 = MFMA32(a, bb1, f1);
    }
  }
  u32x8 res0, res1;     // residual state for this sub's 32 channels
  first_epi(f0, res0, sub, p0, ids0, img, imgbase, hi, sm, first_s, first_b, act0);
  first_epi(f1, res1, sub, p1, ids1, img, imgbase, hi, sm, first_s, first_b, act0);
  __syncthreads();      // xin dead; ring DMA may start

  stage_tile(sm, wstream, 0, wave, lane);
  stage_tile(sm, wstream, 1, wave, lane);

  // ---- residual tower: staged weight-tile stream, mt-split across wave pair ----
  f32x16 c0 = {}, c1 = {};
  int dy = 0, dx = 0, L = 0, st = 0;
  for (int s = 0; s < NTILES; ++s){
    if (s + 2 < NTILES) stage_tile(sm, wstream, s + 2, wave, lane);
    if (s < NTILES - 2)       asm volatile("s_waitcnt vmcnt(2)" ::: "memory");
    else if (s == NTILES - 2) asm volatile("s_waitcnt vmcnt(1)" ::: "memory");
    else                      asm volatile("s_waitcnt vmcnt(0)" ::: "memory");
    __builtin_amdgcn_s_barrier();
    asm volatile("" ::: "memory");
    const unsigned short* wb = (const unsigned short*)(sm + WBUF_OFF + (s % 3)*8192);
    int r = s - st*344;
    if (r < 343){
      // conv tap (dy,dx) of layer L; this wave does mt=sub only
      bool v0 = ((unsigned)(y0 + dy - 3) < 8u) && ((unsigned)(x0v + dx - 3) < 8u);
      bool v1 = ((unsigned)(y1 + dy - 3) < 8u) && ((unsigned)(x1v + dx - 3) < 8u);
      int off = (dy - 3)*8 + (dx - 3);
      bf16x8 ak[4];
      #pragma unroll
      for (int ks = 0; ks < 4; ++ks)
        ak[ks] = *(const bf16x8*)(wb + (ks*2 + sub)*512 + lane*8);
      int b0 = baddr(p0 + off, v0, imgbase, hi);
      int b1 = baddr(p1 + off, v1, imgbase, hi);
      #pragma unroll
      for (int ks = 0; ks < 4; ++ks){
        bf16x8 bf0 = *(const bf16x8*)(sm + (b0 ^ (ks << 5)));
        bf16x8 bf1 = *(const bf16x8*)(sm + (b1 ^ (ks << 5)));
        c0 = MFMA32(ak[ks], bf0, c0);
        c1 = MFMA32(ak[ks], bf1, c1);
      }
      ++dx;
      if (dx == 7){ dx = 0; ++dy; }
      if (dy == 7){
        dy = 0;
        const float* sp = res_s + L*64;
        const float* bp = res_b + L*64;
        conv_epi(c0, sub, p0, imgbase, hi, sm, sp, bp);
        conv_epi(c1, sub, p1, imgbase, hi, sm, sp, bp);
        c0 = f32x16{}; c1 = f32x16{};
        ++L;
      }
    } else {
      // 1x1 (last_w) + bn + residual + relu
      const float* lsp = last_s + st*64;
      const float* lbp = last_b + st*64;
      f32x16 d0 = {}, d1 = {};
      int bA = baddr(p0, true, imgbase, hi);
      int bB = baddr(p1, true, imgbase, hi);
      #pragma unroll
      for (int ks = 0; ks < 4; ++ks){
        bf16x8 a  = *(const bf16x8*)(wb + (ks*2 + sub)*512 + lane*8);
        bf16x8 b0 = *(const bf16x8*)(sm + (bA ^ (ks << 5)));
        bf16x8 b1 = *(const bf16x8*)(sm + (bB ^ (ks << 5)));
        d0 = MFMA32(a, b0, d0);
        d1 = MFMA32(a, b1, d1);
      }
      res_epi(d0, res0, sub, p0, imgbase, hi, sm, lsp, lbp);
      res_epi(d1, res1, sub, p1, imgbase, hi, sm, lsp, lbp);
      ++st;
    }
    // drain LDS writes so the partner sub sees epilogue stores after the barrier
    asm volatile("s_waitcnt lgkmcnt(0)" ::: "memory");
    __builtin_amdgcn_s_barrier();
    asm volatile("" ::: "memory");
  }

  // ---- value head ----
  float part0 = 0.f, part1 = 0.f;
  #pragma unroll
  for (int rg = 0; rg < 4; ++rg){
    #pragma unroll
    for (int eh = 0; eh < 2; ++eh){
      unsigned pA0 = res0[rg*2+eh], pA1 = res1[rg*2+eh];
      int ob = sub*32 + rg*8 + hi*4 + eh*2;
      float w0 = vconv_w[ob], w1 = vconv_w[ob+1];
      part0 += bf2f((unsigned short)(pA0 & 0xffffu))*w0 + bf2f((unsigned short)(pA0 >> 16))*w1;
      part1 += bf2f((unsigned short)(pA1 & 0xffffu))*w0 + bf2f((unsigned short)(pA1 >> 16))*w1;
    }
  }
  part0 += __shfl_xor(part0, 32);
  part1 += __shfl_xor(part1, 32);
  float* vp = (float*)(sm + WBUF_OFF);      // [imgi][sub][64]
  float pv = hi ? part1 : part0;
  vp[(imgi*2 + sub)*64 + hi*32 + col] = pv;
  __syncthreads();

  if (wave < 4){                             // sub0 waves finish their own image
    int mimg = blockIdx.x*4 + wave;
    float vs = v_s[0], vb = v_b[0];
    float sum = vp[(wave*2)*64 + lane] + vp[(wave*2 + 1)*64 + lane];
    float vv = vs*sum + vb; vv = vv > 0.f ? vv : 0.f;
    float* vbuf = (float*)(sm + WBUF_OFF + 2048) + wave*64;
    vbuf[lane] = vv;
    float hidv[4];
    #pragma unroll
    for (int it = 0; it < 4; ++it){
      int jj = it*64 + lane;
      float a = vfc1_b[jj];
      for (int k = 0; k < 64; k += 4){
        float4v vv4 = *(const float4v*)(vbuf + k);
        a += vfc1_w[jj*64+k]*vv4[0] + vfc1_w[jj*64+k+1]*vv4[1]
           + vfc1_w[jj*64+k+2]*vv4[2] + vfc1_w[jj*64+k+3]*vv4[3];
      }
      hidv[it] = a > 0.f ? a : 0.f;
    }
    float tot = 0.f;
    #pragma unroll
    for (int it = 0; it < 4; ++it) tot += hidv[it]*vfc2_w[it*64 + lane];
    #pragma unroll
    for (int off = 32; off; off >>= 1) tot += __shfl_xor(tot, off);
    if (lane == 0) value_out[mimg] = tanhf(tot + vfc2_b[0]);
  }
}

// ======================= gather / piece head =======================
__global__ __launch_bounds__(256) void gather_k(const unsigned short* __restrict__ act0,
                                                unsigned short* __restrict__ pvec,
                                                float* __restrict__ pid_out){
  int lane = threadIdx.x & 63, wave = threadIdx.x >> 6;
  int img = blockIdx.x*4 + wave;
  const unsigned short* arow = act0 + (size_t)img*4096;
  int myid = (int)bf2f(arow[lane*64 + 63]);
  int mypos = 0, mypres = 0;
  for (int p = 0; p < 32; ++p){
    unsigned long long m = __ballot(myid == (p+1));
    if (lane == p){ mypres = (m != 0ull); mypos = mypres ? (__ffsll(m) - 1) : 0; }
  }
  if (lane < 32){
    float v = mypres ? (float)(lane+1) : 0.f;
    #pragma unroll
    for (int s = 0; s < 8; ++s) pid_out[(size_t)img*256 + s*32 + lane] = v;
  }
  for (int p = 0; p < 32; ++p){
    int q  = __shfl(mypos, p);
    int pr = __shfl(mypres, p);
    unsigned short v = pr ? arow[q*64 + lane] : (unsigned short)0;
    pvec[(size_t)img*2048 + p*64 + lane] = v;
  }
}

// ======================= policy head GEMMs =======================
__global__ __launch_bounds__(256) void fc1_k(const unsigned short* __restrict__ pvec,
                                             const unsigned short* __restrict__ w,
                                             const float* __restrict__ bias,
                                             unsigned short* __restrict__ hid){
  int lane = threadIdx.x & 63, wave = threadIdx.x >> 6;
  int col = lane & 31, hi = lane >> 5;
  int wm = wave >> 1, wn = wave & 1;
  int m0 = blockIdx.x*128 + wm*64;
  int n0 = blockIdx.y*128 + wn*64;
  f32x16 a00 = {}, a01 = {}, a10 = {}, a11 = {};
  for (int k = 0; k < 2048; k += 16){
    bf16x8 A0 = *(const bf16x8*)(pvec + (size_t)(m0+col)*2048    + k + hi*8);
    bf16x8 A1 = *(const bf16x8*)(pvec + (size_t)(m0+32+col)*2048 + k + hi*8);
    bf16x8 B0 = *(const bf16x8*)(w + (size_t)(n0+col)*2048    + k + hi*8);
    bf16x8 B1 = *(const bf16x8*)(w + (size_t)(n0+32+col)*2048 + k + hi*8);
    a00 = MFMA32(A0, B0, a00); a01 = MFMA32(A0, B1, a01);
    a10 = MFMA32(A1, B0, a10); a11 = MFMA32(A1, B1, a11);
  }
  #pragma unroll
  for (int mt = 0; mt < 2; ++mt)
    #pragma unroll
    for (int nt = 0; nt < 2; ++nt){
      const f32x16& acc = mt == 0 ? (nt == 0 ? a00 : a01) : (nt == 0 ? a10 : a11);
      int jcol = n0 + nt*32 + col;
      float bj = bias[jcol];
      #pragma unroll
      for (int rg = 0; rg < 4; ++rg)
        #pragma unroll
        for (int e = 0; e < 4; ++e){
          int n = m0 + mt*32 + rg*8 + hi*4 + e;
          float v = acc[rg*4+e] + bj; v = v > 0.f ? v : 0.f;
          hid[(size_t)n*256 + jcol] = f2bf(v);
        }
    }
}

__global__ __launch_bounds__(256) void fc2_k(const unsigned short* __restrict__ hid,
                                             const unsigned short* __restrict__ w,
                                             const float* __restrict__ bias,
                                             float* __restrict__ pol){
  int lane = threadIdx.x & 63, wave = threadIdx.x >> 6;
  int col = lane & 31, hi = lane >> 5;
  int wm = wave >> 1, wn = wave & 1;
  int m0 = blockIdx.x*128 + wm*64;
  int n0 = blockIdx.y*128 + wn*64;
  f32x16 a00 = {}, a01 = {}, a10 = {}, a11 = {};
  for (int k = 0; k < 256; k += 16){
    bf16x8 A0 = *(const bf16x8*)(hid + (size_t)(m0+col)*256    + k + hi*8);
    bf16x8 A1 = *(const bf16x8*)(hid + (size_t)(m0+32+col)*256 + k + hi*8);
    bf16x8 B0 = *(const bf16x8*)(w + (size_t)(n0+col)*256    + k + hi*8);
    bf16x8 B1 = *(const bf16x8*)(w + (size_t)(n0+32+col)*256 + k + hi*8);
    a00 = MFMA32(A0, B0, a00); a01 = MFMA32(A0, B1, a01);
    a10 = MFMA32(A1, B0, a10); a11 = MFMA32(A1, B1, a11);
  }
  #pragma unroll
  for (int mt = 0; mt < 2; ++mt)
    #pragma unroll
    for (int nt = 0; nt < 2; ++nt){
      const f32x16& acc = mt == 0 ? (nt == 0 ? a00 : a01) : (nt == 0 ? a10 : a11);
      int jcol = n0 + nt*32 + col;
      if (jcol < 1700){
        float bj = bias[jcol];
        #pragma unroll
        for (int rg = 0; rg < 4; ++rg)
          #pragma unroll
          for (int e = 0; e < 4; ++e){
            int n = m0 + mt*32 + rg*8 + hi*4 + e;
            pol[(size_t)n*1700 + jcol] = acc[rg*4+e] + bj;
          }
      }
    }
}

// ======================= launch =======================
extern "C" void kernel_launch(void* const* d_in, const int* in_sizes, int n_in,
                              void* d_out, int out_size, void* d_ws, size_t ws_size,
                              hipStream_t stream){
  const float* x       = (const float*)d_in[0];
  const float* first_w = (const float*)d_in[1];
  const float* first_s = (const float*)d_in[2];
  const float* first_b = (const float*)d_in[3];
  const float* res_w   = (const float*)d_in[4];
  const float* res_s   = (const float*)d_in[5];
  const float* res_b   = (const float*)d_in[6];
  const float* last_w  = (const float*)d_in[7];
  const float* last_s  = (const float*)d_in[8];
  const float* last_b  = (const float*)d_in[9];
  const float* pfc1_w  = (const float*)d_in[10];
  const float* pfc1_b  = (const float*)d_in[11];
  const float* pfc2_w  = (const float*)d_in[12];
  const float* pfc2_b  = (const float*)d_in[13];
  const float* vconv_w = (const float*)d_in[14];
  const float* v_s     = (const float*)d_in[15];
  const float* v_b     = (const float*)d_in[16];
  const float* vfc1_w  = (const float*)d_in[17];
  const float* vfc1_b  = (const float*)d_in[18];
  const float* vfc2_w  = (const float*)d_in[19];
  const float* vfc2_b  = (const float*)d_in[20];
  unsigned short* ws = (unsigned short*)d_ws;
  float* out = (float*)d_out;

  prep_res_k <<<3136, 256, 0, stream>>>(res_w, ws);
  prep_misc_k<<<1024, 256, 0, stream>>>(first_w, last_w, pfc1_w, pfc2_w, ws);
  tower_k    <<<256, 512, 0, stream>>>(x, first_s, first_b, res_s, res_b, last_s, last_b,
                                       vconv_w, v_s, v_b, vfc1_w, vfc1_b, vfc2_w, vfc2_b,
                                       ws, ws + ACT0_OFF, out + VAL_OFF);
  gather_k   <<<256, 256, 0, stream>>>(ws + ACT0_OFF, ws + PV_OFF, out + PID_OFF);
  fc1_k      <<<dim3(8, 2), 256, 0, stream>>>(ws + PV_OFF, ws + P1_OFF, pfc1_b, ws + HID_OFF);
  fc2_k      <<<dim3(8, 14), 256, 0, stream>>>(ws + HID_OFF, ws + P2_OFF, pfc2_b, out);
}

// Round 5
// 1398.546 us; speedup vs baseline: 2.2411x; 1.2161x over previous
//
#include <hip/hip_runtime.h>

typedef __attribute__((ext_vector_type(8)))  short          bf16x8;
typedef __attribute__((ext_vector_type(16))) float          f32x16;
typedef __attribute__((ext_vector_type(8)))  unsigned int   u32x8;
typedef __attribute__((ext_vector_type(4)))  unsigned short ushort4v;
typedef __attribute__((ext_vector_type(4)))  float          float4v;

#define DEV static __device__ __forceinline__
#define MFMA32(A,B,C) __builtin_amdgcn_mfma_f32_32x32x16_bf16(A,B,C,0,0,0)

// ---- workspace element offsets (unsigned short elements) ----
// WRES: weight tile STREAM in exact consumption order:
//   for st in 0..6: 343 conv tiles (7 layers x 49 taps) + 1 last_w tile
//   = 2408 tiles x 4096 shorts (8KB) each, frag-major [frag(ks*2+mt)][lane][8]
#define NTILES   2408
#define WRES_OFF 0u           // 2408 * 4096                        = 9,863,168
#define FW_OFF   9863168u     // 49 taps * 2 frag * 64 lane * 8     =    50,176
#define P1_OFF   9913344u     // 256 * 2048                         =   524,288
#define P2_OFF   10437632u    // 1792 * 256 (padded rows)           =   458,752
#define ACT0_OFF 10896384u    // 1024 * 64p * 64c                   = 4,194,304
#define PV_OFF   15090688u    // 1024 * 32 * 64                     = 2,097,152
#define HID_OFF  17187840u    // 1024 * 256                         =   262,144
// total 17,449,984 ushorts = 34.9 MB

// ---- d_out offsets (floats) ----
#define VAL_OFF 1740800
#define PID_OFF 1741824

// ---- tower LDS map ----
// double-buffered acts: 2 bufs x 4 img x 64 rows x 128B; zero row after.
// xin staging (4 x 3584) and value-head buffers overlay ACT_B (dead then).
#define ACT_A    0
#define ACT_B    32768
#define SM_Z     65536
#define SM_BYTES 65792

DEV float bf2f(unsigned short u){ union { unsigned int i; float f; } v; v.i = ((unsigned int)u) << 16; return v.f; }
DEV unsigned short f2bf(float f){
  union { float f; unsigned int i; } v; v.f = f;
  unsigned int x = v.i;
  return (unsigned short)((x + 0x7fffu + ((x >> 16) & 1u)) >> 16);  // RNE
}

// ======================= weight prep =======================
// res_w (7,7,64,64,7,7) f32 -> stream tile (L*49+t+L/7), frag-major:
// element (lane,j) of frag (ks*2+mt) = W[o = mt*32 + (lane&31)][c = ks*16 + (lane>>5)*8 + j]
__global__ void prep_res_k(const float* __restrict__ res_w, unsigned short* __restrict__ ws){
  __shared__ float buf[3136];
  int bx = blockIdx.x;             // L*64 + o
  int L = bx >> 6, o = bx & 63;
  const float* src = res_w + (size_t)bx * 3136;   // (o fixed): [c][dy][dx] contiguous
  for (int e = threadIdx.x; e < 3136; e += 256) buf[e] = src[e];
  __syncthreads();
  unsigned short* dst = ws + WRES_OFF;
  int mt = o >> 5, lrow = o & 31;
  int tilebase = L*49 + L/7;
  for (int e = threadIdx.x; e < 3136; e += 256){
    int t = e >> 6, c = e & 63;
    int ks = c >> 4, hi = (c >> 3) & 1, j = c & 7;
    int lane = hi*32 + lrow;
    dst[(size_t)(tilebase + t)*4096 + ((ks*2 + mt)*64 + lane)*8 + j] = f2bf(buf[c*49 + t]);
  }
}

// first_w -> fw[t][mt][lane][8] (K=16: c = (lane>>5)*8+j, 12 real + 4 zero)
// last_w  -> stream tile (st*344+343), frag-major
// pfc1/pfc2 cast (+pad)
__global__ void prep_misc_k(const float* __restrict__ first_w, const float* __restrict__ last_w,
                            const float* __restrict__ pfc1_w, const float* __restrict__ pfc2_w,
                            unsigned short* __restrict__ ws){
  const int n_fw = 49*1024, n_lw = 28672, n_p1 = 524288, n_p2 = 458752;
  const int total = n_fw + n_lw + n_p1 + n_p2;
  for (int d = blockIdx.x*256 + threadIdx.x; d < total; d += gridDim.x*256){
    if (d < n_fw){
      int t = d >> 10, r = d & 1023;
      int mt = r >> 9, lane = (r >> 3) & 63, j = r & 7;
      int o = mt*32 + (lane & 31);
      int c = ((lane >> 5) << 3) + j;
      float v = (o < 63 && c < 12) ? first_w[(o*12 + c)*49 + t] : 0.f;
      ws[FW_OFF + d] = f2bf(v);
    } else if (d < n_fw + n_lw){
      int e = d - n_fw;
      int st = e >> 12, r = e & 4095;
      int f = r >> 9, lane = (r >> 3) & 63, j = r & 7;
      int ks = f >> 1, mt = f & 1;
      int o = mt*32 + (lane & 31);
      int c = ks*16 + ((lane >> 5) << 3) + j;
      ws[WRES_OFF + (size_t)(st*344 + 343)*4096 + r] = f2bf(last_w[st*4096 + o*64 + c]);
    } else if (d < n_fw + n_lw + n_p1){
      int e = d - n_fw - n_lw; ws[P1_OFF + e] = f2bf(pfc1_w[e]);
    } else {
      int e = d - n_fw - n_lw - n_p1;
      int row = e >> 8, k = e & 255;
      ws[P2_OFF + e] = f2bf(row < 1700 ? pfc2_w[row*256 + k] : 0.f);
    }
  }
}

// ======================= tower =======================

// load the 4 ks A-frags of one tile for this wave's mt half (q in shorts)
#define LOADW(W, q) { \
  W[0] = *(const bf16x8*)(q); \
  W[1] = *(const bf16x8*)((q) + 1024); \
  W[2] = *(const bf16x8*)((q) + 2048); \
  W[3] = *(const bf16x8*)((q) + 3072); }

// one conv tap: 4 LDS B-reads + 4 MFMAs into c0 (dy,dx compile-time)
#define TAPB(W, dyc, dxc) { \
  bool v_ = ((unsigned)(py + (dyc) - 3) < 8u) && ((unsigned)(px + (dxc) - 3) < 8u); \
  int pp_ = p + ((dyc) - 3)*8 + ((dxc) - 3); \
  int b_ = v_ ? (rbase + (pp_ << 7) + (hi16 ^ ((pp_ & 7) << 4))) : zaddr; \
  c0 = MFMA32(W[0], *(const bf16x8*)(sm + b_),        c0); \
  c0 = MFMA32(W[1], *(const bf16x8*)(sm + (b_ ^ 32)), c0); \
  c0 = MFMA32(W[2], *(const bf16x8*)(sm + (b_ ^ 64)), c0); \
  c0 = MFMA32(W[3], *(const bf16x8*)(sm + (b_ ^ 96)), c0); }

#define LBAR() { asm volatile("s_waitcnt lgkmcnt(0)" ::: "memory"); \
                 __builtin_amdgcn_s_barrier(); \
                 asm volatile("" ::: "memory"); }

DEV void conv_epi(const f32x16& acc, int sub, int p, int wrow, int hi,
                  unsigned char* smp, const float* sp, const float* bp){
  int swzw = (p & 7) << 4;
  #pragma unroll
  for (int rg = 0; rg < 4; ++rg){
    int o0 = sub*32 + rg*8 + hi*4;
    unsigned short bb[4];
    #pragma unroll
    for (int e = 0; e < 4; ++e){
      float v = sp[o0+e]*acc[rg*4+e] + bp[o0+e];
      v = v > 0.f ? v : 0.f;
      bb[e] = f2bf(v);
    }
    int ob = sub*64 + rg*16 + hi*8;
    *(ushort4v*)(smp + wrow + (ob ^ swzw)) = ushort4v{bb[0],bb[1],bb[2],bb[3]};
  }
}

DEV void res_epi(const f32x16& acc, u32x8& res, int sub, int p, int wrow, int hi,
                 unsigned char* smp, const float* lsp, const float* lbp){
  int swzw = (p & 7) << 4;
  #pragma unroll
  for (int rg = 0; rg < 4; ++rg){
    int o0 = sub*32 + rg*8 + hi*4;
    unsigned short bb[4];
    #pragma unroll
    for (int e = 0; e < 4; ++e){
      unsigned pr = res[rg*2 + (e>>1)];
      float rv = bf2f((unsigned short)((e & 1) ? (pr >> 16) : (pr & 0xffffu)));
      float v = lsp[o0+e]*acc[rg*4+e] + lbp[o0+e] + rv;
      v = v > 0.f ? v : 0.f;
      bb[e] = f2bf(v);
    }
    res[rg*2]   = (unsigned)bb[0] | ((unsigned)bb[1] << 16);
    res[rg*2+1] = (unsigned)bb[2] | ((unsigned)bb[3] << 16);
    int ob = sub*64 + rg*16 + hi*8;
    *(ushort4v*)(smp + wrow + (ob ^ swzw)) = ushort4v{bb[0],bb[1],bb[2],bb[3]};
  }
}

DEV void first_epi(const f32x16& acc, u32x8& res, int sub, int p, float idsv,
                   int img, int wrow, int hi, unsigned char* smp,
                   const float* fsp, const float* fbp, unsigned short* act0){
  int swzw = (p & 7) << 4;
  #pragma unroll
  for (int rg = 0; rg < 4; ++rg){
    int o0 = sub*32 + rg*8 + hi*4;
    unsigned short bb[4];
    #pragma unroll
    for (int e = 0; e < 4; ++e){
      int o = o0 + e;
      int oc = o < 63 ? o : 62;          // avoid OOB load of 63-entry arrays
      float v = fsp[oc]*acc[rg*4+e] + fbp[oc];
      v = v > 0.f ? v : 0.f;
      if (o == 63) v = idsv;             // ids channel, no bn/relu
      bb[e] = f2bf(v);
    }
    res[rg*2]   = (unsigned)bb[0] | ((unsigned)bb[1] << 16);
    res[rg*2+1] = (unsigned)bb[2] | ((unsigned)bb[3] << 16);
    int ob = sub*64 + rg*16 + hi*8;
    *(ushort4v*)(smp + wrow + (ob ^ swzw)) = ushort4v{bb[0],bb[1],bb[2],bb[3]};
    *(ushort4v*)(act0 + (size_t)img*4096 + p*64 + o0) = ushort4v{bb[0],bb[1],bb[2],bb[3]};
  }
}

__global__ __launch_bounds__(1024, 4) void tower_k(
    const float* __restrict__ x,
    const float* __restrict__ first_s, const float* __restrict__ first_b,
    const float* __restrict__ res_s,   const float* __restrict__ res_b,
    const float* __restrict__ last_s,  const float* __restrict__ last_b,
    const float* __restrict__ vconv_w, const float* __restrict__ v_s, const float* __restrict__ v_b,
    const float* __restrict__ vfc1_w,  const float* __restrict__ vfc1_b,
    const float* __restrict__ vfc2_w,  const float* __restrict__ vfc2_b,
    const unsigned short* __restrict__ ws_r, unsigned short* __restrict__ act0,
    float* __restrict__ value_out)
{
  __shared__ unsigned char sm[SM_BYTES];
  int tid = threadIdx.x, lane = tid & 63, wave = tid >> 6;
  int imgi = wave & 3, sub = (wave >> 2) & 1, pg = wave >> 3;   // quadrant decomposition
  int img = blockIdx.x * 4 + imgi;

  for (int i = tid*16; i < SM_BYTES; i += 1024*16) *(float4v*)(sm + i) = float4v{0,0,0,0};
  __syncthreads();

  int col = lane & 31, hi = lane >> 5;
  int hi16 = hi << 4;
  int zaddr = SM_Z + hi16;
  int p  = pg*32 + col;               // my position (0..63)
  int py = p >> 3, px = p & 7;

  // ---- stage x into padded xin (bf16, overlays ACT_B), channels 0..11 ----
  const float* xim = x + (size_t)img * 832;
  int xinbase = ACT_B + imgi * 3584;
  if (wave < 4){
    int q = (lane >> 3)*14 + (lane & 7) + 3;
    for (int c = 0; c < 12; ++c)
      *(unsigned short*)(sm + xinbase + q*32 + c*2) = f2bf(xim[c*64 + lane]);
  }
  float idsv = xim[768 + p];
  __syncthreads();

  // ---- first conv (K=16): each wave computes its (pg, sub) quadrant ----
  f32x16 f0 = {};
  const unsigned short* fw = ws_r + FW_OFF;
  int qbx = py*14 + px;
  #pragma unroll
  for (int dy = 0; dy < 7; ++dy){
    bool vy = (unsigned)(py + dy - 3) < 8u;
    int tq = (dy-3)*14;
    #pragma unroll
    for (int dx = 0; dx < 7; ++dx){
      int t = dy*7 + dx;
      bf16x8 a = *(const bf16x8*)(fw + t*1024 + sub*512 + lane*8);
      int q0 = qbx + tq + dx;
      int ba = vy ? (xinbase + q0*32 + hi16) : zaddr;
      f0 = MFMA32(a, *(const bf16x8*)(sm + ba), f0);
    }
  }
  u32x8 res0;
  first_epi(f0, res0, sub, p, idsv, img, ACT_A + imgi*8192 + (p << 7), hi, sm,
            first_s, first_b, act0);
  __syncthreads();

  // ---- residual tower: A-frags global->VGPR (2-deep prefetch), B from dbuf acts ----
  int rbase = ACT_A + imgi*8192;
  int wbase = ACT_B + imgi*8192;
  const unsigned short* gw = ws_r + WRES_OFF + sub*512 + lane*8;

  for (int st = 0; st < 7; ++st){
    for (int j = 0; j < 7; ++j){
      int L = st*7 + j;
      f32x16 c0 = {};
      bf16x8 wA[4], wB[4];
      LOADW(wA, gw);
      #pragma unroll
      for (int t = 0; t < 49; ++t){
        const int dy = t / 7, dx = t % 7;
        if ((t & 1) == 0){
          if (t + 1 < 49) LOADW(wB, gw + (t+1)*4096);
          TAPB(wA, dy, dx);
        } else {
          if (t + 1 < 49) LOADW(wA, gw + (t+1)*4096);
          TAPB(wB, dy, dx);
        }
      }
      gw += 49*4096;
      conv_epi(c0, sub, p, wbase + (p << 7), hi, sm, res_s + L*64, res_b + L*64);
      LBAR();
      int tmpb = rbase; rbase = wbase; wbase = tmpb;
    }
    // 1x1 (last_w) + bn + residual + relu
    {
      bf16x8 wA[4];
      LOADW(wA, gw); gw += 4096;
      f32x16 d0 = {};
      int b = rbase + (p << 7) + (hi16 ^ ((p & 7) << 4));
      d0 = MFMA32(wA[0], *(const bf16x8*)(sm + b),        d0);
      d0 = MFMA32(wA[1], *(const bf16x8*)(sm + (b ^ 32)), d0);
      d0 = MFMA32(wA[2], *(const bf16x8*)(sm + (b ^ 64)), d0);
      d0 = MFMA32(wA[3], *(const bf16x8*)(sm + (b ^ 96)), d0);
      res_epi(d0, res0, sub, p, wbase + (p << 7), hi, sm, last_s + st*64, last_b + st*64);
      LBAR();
      int tmpb = rbase; rbase = wbase; wbase = tmpb;
    }
  }

  // ---- value head ----
  float part = 0.f;
  #pragma unroll
  for (int rg = 0; rg < 4; ++rg){
    #pragma unroll
    for (int eh = 0; eh < 2; ++eh){
      unsigned pr = res0[rg*2+eh];
      int ob = sub*32 + rg*8 + hi*4 + eh*2;
      part += bf2f((unsigned short)(pr & 0xffffu))*vconv_w[ob]
            + bf2f((unsigned short)(pr >> 16))*vconv_w[ob+1];
    }
  }
  part += __shfl_xor(part, 32);
  float* vpf = (float*)(sm + ACT_B);          // [imgi][sub][64 pos] (ACT_B dead now)
  if (lane < 32) vpf[(imgi*2 + sub)*64 + pg*32 + lane] = part;
  __syncthreads();

  if (wave < 4){                               // wave w finishes image imgi==w
    int mimg = blockIdx.x*4 + wave;
    float vs = v_s[0], vb = v_b[0];
    float sum = vpf[(wave*2)*64 + lane] + vpf[(wave*2 + 1)*64 + lane];
    float vv = vs*sum + vb; vv = vv > 0.f ? vv : 0.f;
    float* vbuf = (float*)(sm + ACT_B + 2048) + wave*64;
    vbuf[lane] = vv;
    asm volatile("s_waitcnt lgkmcnt(0)" ::: "memory");
    float hidv[4];
    #pragma unroll
    for (int it = 0; it < 4; ++it){
      int jj = it*64 + lane;
      float a = vfc1_b[jj];
      for (int k = 0; k < 64; k += 4){
        float4v vv4 = *(const float4v*)(vbuf + k);
        a += vfc1_w[jj*64+k]*vv4[0] + vfc1_w[jj*64+k+1]*vv4[1]
           + vfc1_w[jj*64+k+2]*vv4[2] + vfc1_w[jj*64+k+3]*vv4[3];
      }
      hidv[it] = a > 0.f ? a : 0.f;
    }
    float tot = 0.f;
    #pragma unroll
    for (int it = 0; it < 4; ++it) tot += hidv[it]*vfc2_w[it*64 + lane];
    #pragma unroll
    for (int off = 32; off; off >>= 1) tot += __shfl_xor(tot, off);
    if (lane == 0) value_out[mimg] = tanhf(tot + vfc2_b[0]);
  }
}

// ======================= gather / piece head =======================
__global__ __launch_bounds__(256) void gather_k(const unsigned short* __restrict__ act0,
                                                unsigned short* __restrict__ pvec,
                                                float* __restrict__ pid_out){
  int lane = threadIdx.x & 63, wave = threadIdx.x >> 6;
  int img = blockIdx.x*4 + wave;
  const unsigned short* arow = act0 + (size_t)img*4096;
  int myid = (int)bf2f(arow[lane*64 + 63]);
  int mypos = 0, mypres = 0;
  for (int p = 0; p < 32; ++p){
    unsigned long long m = __ballot(myid == (p+1));
    if (lane == p){ mypres = (m != 0ull); mypos = mypres ? (__ffsll(m) - 1) : 0; }
  }
  if (lane < 32){
    float v = mypres ? (float)(lane+1) : 0.f;
    #pragma unroll
    for (int s = 0; s < 8; ++s) pid_out[(size_t)img*256 + s*32 + lane] = v;
  }
  for (int p = 0; p < 32; ++p){
    int q  = __shfl(mypos, p);
    int pr = __shfl(mypres, p);
    unsigned short v = pr ? arow[q*64 + lane] : (unsigned short)0;
    pvec[(size_t)img*2048 + p*64 + lane] = v;
  }
}

// ======================= policy head GEMMs =======================
__global__ __launch_bounds__(256) void fc1_k(const unsigned short* __restrict__ pvec,
                                             const unsigned short* __restrict__ w,
                                             const float* __restrict__ bias,
                                             unsigned short* __restrict__ hid){
  int lane = threadIdx.x & 63, wave = threadIdx.x >> 6;
  int col = lane & 31, hi = lane >> 5;
  int wm = wave >> 1, wn = wave & 1;
  int m0 = blockIdx.x*128 + wm*64;
  int n0 = blockIdx.y*128 + wn*64;
  f32x16 a00 = {}, a01 = {}, a10 = {}, a11 = {};
  for (int k = 0; k < 2048; k += 16){
    bf16x8 A0 = *(const bf16x8*)(pvec + (size_t)(m0+col)*2048    + k + hi*8);
    bf16x8 A1 = *(const bf16x8*)(pvec + (size_t)(m0+32+col)*2048 + k + hi*8);
    bf16x8 B0 = *(const bf16x8*)(w + (size_t)(n0+col)*2048    + k + hi*8);
    bf16x8 B1 = *(const bf16x8*)(w + (size_t)(n0+32+col)*2048 + k + hi*8);
    a00 = MFMA32(A0, B0, a00); a01 = MFMA32(A0, B1, a01);
    a10 = MFMA32(A1, B0, a10); a11 = MFMA32(A1, B1, a11);
  }
  #pragma unroll
  for (int mt = 0; mt < 2; ++mt)
    #pragma unroll
    for (int nt = 0; nt < 2; ++nt){
      const f32x16& acc = mt == 0 ? (nt == 0 ? a00 : a01) : (nt == 0 ? a10 : a11);
      int jcol = n0 + nt*32 + col;
      float bj = bias[jcol];
      #pragma unroll
      for (int rg = 0; rg < 4; ++rg)
        #pragma unroll
        for (int e = 0; e < 4; ++e){
          int n = m0 + mt*32 + rg*8 + hi*4 + e;
          float v = acc[rg*4+e] + bj; v = v > 0.f ? v : 0.f;
          hid[(size_t)n*256 + jcol] = f2bf(v);
        }
    }
}

__global__ __launch_bounds__(256) void fc2_k(const unsigned short* __restrict__ hid,
                                             const unsigned short* __restrict__ w,
                                             const float* __restrict__ bias,
                                             float* __restrict__ pol){
  int lane = threadIdx.x & 63, wave = threadIdx.x >> 6;
  int col = lane & 31, hi = lane >> 5;
  int wm = wave >> 1, wn = wave & 1;
  int m0 = blockIdx.x*128 + wm*64;
  int n0 = blockIdx.y*128 + wn*64;
  f32x16 a00 = {}, a01 = {}, a10 = {}, a11 = {};
  for (int k = 0; k < 256; k += 16){
    bf16x8 A0 = *(const bf16x8*)(hid + (size_t)(m0+col)*256    + k + hi*8);
    bf16x8 A1 = *(const bf16x8*)(hid + (size_t)(m0+32+col)*256 + k + hi*8);
    bf16x8 B0 = *(const bf16x8*)(w + (size_t)(n0+col)*256    + k + hi*8);
    bf16x8 B1 = *(const bf16x8*)(w + (size_t)(n0+32+col)*256 + k + hi*8);
    a00 = MFMA32(A0, B0, a00); a01 = MFMA32(A0, B1, a01);
    a10 = MFMA32(A1, B0, a10); a11 = MFMA32(A1, B1, a11);
  }
  #pragma unroll
  for (int mt = 0; mt < 2; ++mt)
    #pragma unroll
    for (int nt = 0; nt < 2; ++nt){
      const f32x16& acc = mt == 0 ? (nt == 0 ? a00 : a01) : (nt == 0 ? a10 : a11);
      int jcol = n0 + nt*32 + col;
      if (jcol < 1700){
        float bj = bias[jcol];
        #pragma unroll
        for (int rg = 0; rg < 4; ++rg)
          #pragma unroll
          for (int e = 0; e < 4; ++e){
            int n = m0 + mt*32 + rg*8 + hi*4 + e;
            pol[(size_t)n*1700 + jcol] = acc[rg*4+e] + bj;
          }
      }
    }
}

// ======================= launch =======================
extern "C" void kernel_launch(void* const* d_in, const int* in_sizes, int n_in,
                              void* d_out, int out_size, void* d_ws, size_t ws_size,
                              hipStream_t stream){
  const float* x       = (const float*)d_in[0];
  const float* first_w = (const float*)d_in[1];
  const float* first_s = (const float*)d_in[2];
  const float* first_b = (const float*)d_in[3];
  const float* res_w   = (const float*)d_in[4];
  const float* res_s   = (const float*)d_in[5];
  const float* res_b   = (const float*)d_in[6];
  const float* last_w  = (const float*)d_in[7];
  const float* last_s  = (const float*)d_in[8];
  const float* last_b  = (const float*)d_in[9];
  const float* pfc1_w  = (const float*)d_in[10];
  const float* pfc1_b  = (const float*)d_in[11];
  const float* pfc2_w  = (const float*)d_in[12];
  const float* pfc2_b  = (const float*)d_in[13];
  const float* vconv_w = (const float*)d_in[14];
  const float* v_s     = (const float*)d_in[15];
  const float* v_b     = (const float*)d_in[16];
  const float* vfc1_w  = (const float*)d_in[17];
  const float* vfc1_b  = (const float*)d_in[18];
  const float* vfc2_w  = (const float*)d_in[19];
  const float* vfc2_b  = (const float*)d_in[20];
  unsigned short* ws = (unsigned short*)d_ws;
  float* out = (float*)d_out;

  prep_res_k <<<3136, 256, 0, stream>>>(res_w, ws);
  prep_misc_k<<<1024, 256, 0, stream>>>(first_w, last_w, pfc1_w, pfc2_w, ws);
  tower_k    <<<256, 1024, 0, stream>>>(x, first_s, first_b, res_s, res_b, last_s, last_b,
                                        vconv_w, v_s, v_b, vfc1_w, vfc1_b, vfc2_w, vfc2_b,
                                        ws, ws + ACT0_OFF, out + VAL_OFF);
  gather_k   <<<256, 256, 0, stream>>>(ws + ACT0_OFF, ws + PV_OFF, out + PID_OFF);
  fc1_k      <<<dim3(8, 2), 256, 0, stream>>>(ws + PV_OFF, ws + P1_OFF, pfc1_b, ws + HID_OFF);
  fc2_k      <<<dim3(8, 14), 256, 0, stream>>>(ws + HID_OFF, ws + P2_OFF, pfc2_b, out);
}